// Round 9
// baseline (6373.859 us; speedup 1.0000x reference)
//
#include <hip/hip_runtime.h>
#include <hip/hip_cooperative_groups.h>
#include <math.h>

namespace cg = cooperative_groups;

#define NN 325
#define BB 32
#define NB (NN*BB)            // 10400
#define TENC 6
#define TDEC 12
#define WSET 65472            // fp32 Weff: Wzr(340x128)+Wc(340x64)+bzr(128)+bc(64)
#define WT_SET (192*352)      // f16 transposed weights per set
#define M_SET (325*192)       // Mzr[325][128] + Mc[325][64]
#define G16_MAT (384*352)
#define PT_B 765952ull        // 2176*352 f16 per buf
#define PT_E 1531904ull
#define DP_B 3660800ull       // 10400*352 f16 per buf
#define DP_E 7321600ull

typedef _Float16 f16;
typedef f16 f16x4 __attribute__((ext_vector_type(4)));
typedef f16 f16x8 __attribute__((ext_vector_type(8)));
typedef float f32x4 __attribute__((ext_vector_type(4)));

static constexpr float ALPHA = 0.05f;
static constexpr float BETA  = 0.95f;
static constexpr float GAMMA = 0.95f;
static constexpr float ISQ2  = 0.7071067811865476f;

// ---------------- workspace offsets (floats) ----------------
static constexpr size_t OFF_G    = 0;
static constexpr size_t OFF_RS   = OFF_G + 2ull*NN*NN;
static constexpr size_t OFF_RV   = OFF_RS + 650;
static constexpr size_t OFF_WEFF = OFF_RV + 1300;
static constexpr size_t OFF_WT   = OFF_WEFF + 3ull*WSET;
static constexpr size_t OFF_G16  = OFF_WT + (3ull*WT_SET)/2;
static constexpr size_t OFF_M    = OFF_G16 + (4ull*G16_MAT)/2;
static constexpr size_t OFF_WF   = OFF_M + 3ull*M_SET;          // 64*256 f16 -> 8192
static constexpr size_t OFF_TV   = OFF_WF + 8192;               // 576
static constexpr size_t OFF_XS   = OFF_TV + 576;                // 2*6*NB*4 f16
static constexpr size_t OFF_PT   = OFF_XS + (2ull*TENC*NB*4)/2;
static constexpr size_t OFF_DP   = OFF_PT + (2ull*PT_E)/2;
static constexpr size_t OFF_ZR   = OFF_DP + (2ull*DP_E)/2;      // 2*NB*64 fp32 (G2 alias)
static constexpr size_t OFF_HENC = OFF_ZR + 2ull*NB*64;
static constexpr size_t OFF_HDEC = OFF_HENC + 2ull*NB*64;
static constexpr size_t OFF_YS   = OFF_HDEC + (size_t)NB*64;

__device__ inline unsigned pk2(float a, float b) {
    union { f16 h[2]; unsigned u; } x;
    x.h[0] = (f16)a; x.h[1] = (f16)b; return x.u;
}
__device__ inline void st4h(f16* p, float a, float b, float c, float d) {
    f16x4 v; v[0]=(f16)a; v[1]=(f16)b; v[2]=(f16)c; v[3]=(f16)d;
    *(f16x4*)p = v;
}
__device__ inline f16x8 ld8_lds(const f16* p) {
    f16x4 lo = *(const f16x4*)p;
    f16x4 hi = *(const f16x4*)(p + 4);
    f16x8 r;
    r[0]=lo[0]; r[1]=lo[1]; r[2]=lo[2]; r[3]=lo[3];
    r[4]=hi[0]; r[5]=hi[1]; r[6]=hi[2]; r[7]=hi[3];
    return r;
}

// ---------------- prep ----------------
__global__ void k_sums(const float* __restrict__ adj, float* rs, float* cs) {
    int v = blockIdx.x; int t = threadIdx.x;
    float sr = 0.f, sc = 0.f;
    for (int w = t; w < NN; w += 64) { sr += adj[v*NN + w]; sc += adj[w*NN + v]; }
    for (int o = 32; o > 0; o >>= 1) { sr += __shfl_down(sr, o); sc += __shfl_down(sc, o); }
    if (t == 0) { rs[v] = sr + 1.0f; cs[v] = sc + 1.0f; }
}

__global__ void k_buildG(const float* __restrict__ adj, const float* __restrict__ P,
                         const float* __restrict__ rs, const float* __restrict__ cs,
                         float* __restrict__ G) {
    int idx = blockIdx.x*256 + threadIdx.x;
    if (idx >= NN*NN) return;
    int w = idx / NN, v = idx % NN;
    float d = (v == w) ? 1.0f : 0.0f;
    float a1  = (adj[v*NN + w] + d) / rs[v];
    float a1t = (adj[w*NN + v] + d) / cs[v];
    float p = P[v*NN + w];
    G[idx]         = BETA*a1  + GAMMA*p;
    G[NN*NN + idx] = BETA*a1t + GAMMA*p;
}

__global__ __launch_bounds__(256) void k_gg(const float* __restrict__ G, float* __restrict__ G2) {
    int g = blockIdx.z;
    const float* A = G + (size_t)g*NN*NN;
    float* C = G2 + (size_t)g*NN*NN;
    int n0 = blockIdx.y*32, j0 = blockIdx.x*32;
    int tx = threadIdx.x & 31, ty = threadIdx.x >> 5;
    __shared__ float As[32][33];
    __shared__ float Bs[32][33];
    float acc[4] = {};
    for (int k0 = 0; k0 < NN; k0 += 32) {
        for (int l = threadIdx.x; l < 32*32; l += 256) {
            int i = l >> 5, kk = l & 31;
            int n = n0 + i, k = k0 + kk;
            As[i][kk] = (n < NN && k < NN) ? A[(size_t)n*NN + k] : 0.0f;
            int j = j0 + kk;
            Bs[i][kk] = (k0 + i < NN && j < NN) ? A[(size_t)(k0+i)*NN + j] : 0.0f;
        }
        __syncthreads();
        #pragma unroll 8
        for (int kk = 0; kk < 32; kk++) {
            float bv = Bs[kk][tx];
            #pragma unroll
            for (int i = 0; i < 4; i++) acc[i] = fmaf(As[ty + 8*i][kk], bv, acc[i]);
        }
        __syncthreads();
    }
    #pragma unroll
    for (int i = 0; i < 4; i++) {
        int n = n0 + ty + 8*i, j = j0 + tx;
        if (n < NN && j < NN) C[(size_t)n*NN + j] = acc[i];
    }
}

__global__ void k_g16(const float* __restrict__ G, const float* __restrict__ G2,
                      f16* __restrict__ G16) {
    int idx = blockIdx.x*256 + threadIdx.x;
    if (idx >= 4*G16_MAT) return;
    int m = idx / G16_MAT;
    int rem = idx - m*G16_MAT;
    int n = rem / 352, v = rem - n*352;
    int g = m >> 1, s = m & 1;
    float val = 0.0f;
    if (n < NN && v < NN) {
        float gv = G[(size_t)g*NN*NN + n*NN + v];
        float d = (n == v) ? ALPHA : 0.0f;
        val = (s == 0) ? (gv + d)
                       : (G2[(size_t)g*NN*NN + n*NN + v] + ALPHA*gv + d);
    }
    G16[idx] = (f16)val;
}

__global__ void k_rowsum(const float* __restrict__ G, const float* __restrict__ G2,
                         float* __restrict__ rv) {
    int row = blockIdx.x;
    int g = row / NN, n = row - g*NN;
    int t = threadIdx.x;
    float s1 = 0.f, s2 = 0.f;
    for (int v = t; v < NN; v += 64) {
        s1 += G[(size_t)g*NN*NN + n*NN + v];
        s2 += G2[(size_t)g*NN*NN + n*NN + v];
    }
    for (int o = 32; o > 0; o >>= 1) { s1 += __shfl_down(s1, o); s2 += __shfl_down(s2, o); }
    if (t == 0) {
        rv[(g*2 + 0)*NN + n] = ALPHA + s1;
        rv[(g*2 + 1)*NN + n] = ALPHA + ALPHA*s1 + s2;
    }
}

__global__ void k_weff3(const float* __restrict__ W0, const float* __restrict__ b0,
                        const float* __restrict__ W1, const float* __restrict__ b1,
                        const float* __restrict__ W2, const float* __restrict__ b2,
                        float* __restrict__ WeffAll) {
    int s = blockIdx.y;
    const float* W = (s == 0) ? W0 : (s == 1) ? W1 : W2;
    const float* b = (s == 0) ? b0 : (s == 1) ? b1 : b2;
    float* Wset = WeffAll + (size_t)s*WSET;
    float* Wzr = Wset;
    float* Wc  = Wset + 43520;
    float* bzr = Wset + 65280;
    float* bc  = Wset + 65408;
    int tid = blockIdx.x*256 + threadIdx.x;
    if (tid < 340*192) {
        int k = tid / 192, col = tid % 192;
        int g = col >> 6, oo = col & 63;
        const float* Wa = W + (2*g)*204*64;
        const float* Wb = W + (2*g+1)*204*64;
        float val;
        if (k < 68)       val = Wa[k*64+oo] + Wb[k*64+oo];
        else if (k < 204) val = Wa[k*64+oo];
        else              val = Wb[(k-136)*64+oo];
        if (g < 2) Wzr[k*128 + g*64 + oo] = val;
        else       Wc[k*64 + oo] = val;
    }
    if (blockIdx.x == 0 && threadIdx.x < 192) {
        int col = threadIdx.x, g = col >> 6, oo = col & 63;
        float bv = b[(2*g)*64+oo] + b[(2*g+1)*64+oo];
        if (g < 2) bzr[col] = bv; else bc[oo] = bv;
    }
}

__global__ void k_wt3(const float* __restrict__ WeffAll, f16* __restrict__ WtAll) {
    int s = blockIdx.y;
    const float* Weff = WeffAll + (size_t)s*WSET;
    f16* Wt = WtAll + (size_t)s*WT_SET;
    int idx = blockIdx.x*256 + threadIdx.x;
    if (idx >= 192*352) return;
    int o = idx / 352, k = idx - o*352;
    float v = 0.0f;
    if (k < 340) {
        int p = k / 68, c = k - p*68;
        if (c != 3) v = (o < 128) ? Weff[k*128 + o] : Weff[43520 + k*64 + (o - 128)];
    }
    Wt[idx] = (f16)v;
}

__global__ void k_M3(const float* __restrict__ WeffAll, const float* __restrict__ rv,
                     float* __restrict__ MAll) {
    int s = blockIdx.y;
    const float* Weff = WeffAll + (size_t)s*WSET;
    float* M = MAll + (size_t)s*M_SET;
    int idx = blockIdx.x*256 + threadIdx.x;
    if (idx >= 325*192) return;
    int n = idx / 192, q = idx - n*192;
    float acc;
    if (q < 128) {
        int o = q;
        acc = Weff[3*128 + o];
        #pragma unroll
        for (int p = 1; p <= 4; p++)
            acc += rv[(p-1)*NN + n] * Weff[(p*68 + 3)*128 + o];
        M[(size_t)n*128 + o] = acc;
    } else {
        int o = q - 128;
        acc = Weff[43520 + 3*64 + o];
        #pragma unroll
        for (int p = 1; p <= 4; p++)
            acc += rv[(p-1)*NN + n] * Weff[43520 + (p*68 + 3)*64 + o];
        M[325*128 + (size_t)n*64 + o] = acc;
    }
}

__global__ void k_wfuse(const float* __restrict__ Wcam, const float* __restrict__ Wagg,
                        f16* __restrict__ Wf) {
    int idx = blockIdx.x*256 + threadIdx.x;
    if (idx >= 64*256) return;
    int o = idx >> 8, k = idx & 255;
    float v = (k < 128) ? 0.3f*Wcam[(size_t)k*64 + o]
                        : 0.7f*Wagg[(size_t)(k-128)*64 + o];
    Wf[(size_t)o*256 + k] = (f16)v;
}

__global__ void k_tv(const float* __restrict__ st, float* __restrict__ tv) {
    int idx = blockIdx.x*256 + threadIdx.x;
    if (idx >= 18*32) return;
    int b = idx & 31, t = idx >> 5;
    float v;
    if (t < 6) {
        float hour   = (st[b*48 + 24 + 2*t] + 0.5f) * 23.0f;
        float minute = (st[b*48 + 36 + 2*t] + 0.5f) * 59.0f;
        v = floorf((hour*60.0f + minute) / 5.0f);
    } else {
        int td = t - 6;
        v = floorf((st[b*48 + 24 + td] + 0.5f) * 6.0f);
    }
    tv[idx] = v;
}

__global__ void k_xs16(const float* __restrict__ x, f16* __restrict__ xs) {
    int idx = blockIdx.x*256 + threadIdx.x;
    if (idx >= 2*TENC*NB*4) return;
    int c = idx & 3;
    int r = (idx >> 2) % NB;
    int t = (idx / (4*NB)) % TENC;
    int e = idx / (4*NB*TENC);
    int n = r / BB, b = r % BB;
    float val = 0.0f;
    if (c < 3) {
        float xe = x[((b*3 + c)*NN + n)*12 + 2*t];
        float xo = x[((b*3 + c)*NN + n)*12 + 2*t + 1];
        val = (e == 0) ? (xe - xo)*ISQ2 : (xe + xo)*ISQ2;
    }
    xs[idx] = (f16)val;
}

__global__ void k_initH(const float* __restrict__ H1_0, const float* __restrict__ H2_0,
                        float* __restrict__ Henc) {
    int idx = blockIdx.x*256 + threadIdx.x;
    if (idx >= 2*NB*64) return;
    int k = idx & 63;
    int r = (idx >> 6) % NB;
    int e = idx / (NB*64);
    int n = r / BB, b = r % BB;
    const float* src = e ? H2_0 : H1_0;
    Henc[idx] = src[((size_t)b*NN + n)*64 + k];
}

__global__ void k_initDP(const f16* __restrict__ xs, const float* __restrict__ H1_0,
                         const float* __restrict__ H2_0, f16* __restrict__ DP) {
    int idx = blockIdx.x*256 + threadIdx.x;
    if (idx >= 2*NB*92) return;
    int cc = idx % 92;
    int r = (idx / 92) % NB;
    int e = idx / (92*NB);
    int n = r >> 5, b = r & 31;
    f16* D0 = DP + (size_t)e*DP_E;
    if (cc < 68) {
        f16 v;
        if (cc < 3)       v = xs[(size_t)e*TENC*NB*4 + (size_t)r*4 + cc];
        else if (cc == 3) v = (f16)0.0f;
        else {
            const float* h0 = e ? H2_0 : H1_0;
            v = (f16)h0[((size_t)b*NN + n)*64 + (cc-4)];
        }
        D0[(size_t)r*352 + cc] = v;
    } else if (cc < 80) {
        D0[(size_t)r*352 + 340 + (cc-68)] = (f16)0.0f;
    } else {
        D0[DP_B + (size_t)r*352 + 340 + (cc-80)] = (f16)0.0f;
    }
}

__global__ void k_initPT(const f16* __restrict__ xs, const float* __restrict__ H1_0,
                         const float* __restrict__ H2_0, f16* __restrict__ PTb) {
    int idx = blockIdx.x*256 + threadIdx.x;
    if (idx >= 2*2176*352) return;
    int v = idx % 352;
    int j = (idx / 352) % 2176;
    int e = idx / (352*2176);
    f16* P0 = PTb + (size_t)e*PT_E;
    if (v >= NN) {
        P0[(size_t)j*352 + v] = (f16)0.0f;
        P0[PT_B + (size_t)j*352 + v] = (f16)0.0f;
        return;
    }
    int b = j / 68, c = j - b*68;
    f16 val;
    if (c < 3)       val = xs[(size_t)e*TENC*NB*4 + (size_t)(v*32+b)*4 + c];
    else if (c == 3) val = (f16)0.0f;
    else {
        const float* h0 = e ? H2_0 : H1_0;
        val = (f16)h0[((size_t)b*NN + v)*64 + (c-4)];
    }
    P0[(size_t)j*352 + v] = val;
}

// ================= phases (shared by coop kernel and fallback wrappers) =========
struct KParams {
    const f16* G16;
    f16* PT;
    f16* DP;
    const f16* Wt;
    const float* Weff;
    const float* Mw;
    const float* tv;
    float* ZR;
    float* Henc;
    float* Hdec;
    const f16* xs;
    const float* wL; const float* bL; const float* wH; const float* bH;
    const float* bcam; const float* bagg;
    const f16* Wfuse;
    const float* Wfc; const float* bfc;
    float* ys;
    float* out;
};

__device__ void phase_diff(const KParams& p, int par, int E) {
    int tid = threadIdx.x;
    int lane = tid & 63, w = tid >> 6;
    int wm = w >> 1, wn = w & 1;
    int l15 = lane & 15, lk = lane >> 4;
    int ntiles = 34*21*E;
    for (int idx = blockIdx.x; idx < ntiles; idx += gridDim.x) {
        int jt = idx % 34, rem = idx / 34;
        int Rt = rem % 21, e = rem / 21;
        const f16* X = p.PT + (size_t)e*PT_E + (size_t)par*PT_B;
        f16* D = p.DP + (size_t)e*DP_E + (size_t)par*DP_B;
        int j0 = jt*64, R0 = Rt*64;
        const f16* ap[2];
        #pragma unroll
        for (int a = 0; a < 2; a++)
            ap[a] = X + (size_t)(j0 + wm*32 + a*16 + l15)*352;
        const f16* bp[2]; int mv[2], nv[2];
        #pragma unroll
        for (int bt = 0; bt < 2; bt++) {
            int R = R0 + wn*32 + bt*16 + l15;
            int ok = (R < 1300);
            int Rc = ok ? R : 0;
            int m = Rc / 325, n = Rc - m*325;
            mv[bt] = ok ? m : -1; nv[bt] = n;
            bp[bt] = p.G16 + (size_t)m*G16_MAT + (size_t)n*352;
        }
        f32x4 acc[2][2] = {};
        #pragma unroll
        for (int k0 = 0; k0 < 352; k0 += 32) {
            f16x8 af[2], bf[2];
            #pragma unroll
            for (int a = 0; a < 2; a++) af[a] = *(const f16x8*)(ap[a] + k0 + lk*8);
            #pragma unroll
            for (int bt = 0; bt < 2; bt++) bf[bt] = *(const f16x8*)(bp[bt] + k0 + lk*8);
            #pragma unroll
            for (int a = 0; a < 2; a++)
                #pragma unroll
                for (int bt = 0; bt < 2; bt++)
                    acc[a][bt] = __builtin_amdgcn_mfma_f32_16x16x32_f16(af[a], bf[bt], acc[a][bt], 0,0,0);
        }
        #pragma unroll
        for (int bt = 0; bt < 2; bt++) {
            if (mv[bt] < 0) continue;
            int m = mv[bt], n = nv[bt];
            #pragma unroll
            for (int a = 0; a < 2; a++) {
                int jb = j0 + wm*32 + a*16 + lk*4;
                int b = jb / 68, c = jb - b*68;
                f16* dst = D + (size_t)(n*32 + b)*352 + (m+1)*68 + c;
                st4h(dst, acc[a][bt][0], acc[a][bt][1], acc[a][bt][2], acc[a][bt][3]);
            }
        }
    }
}

__device__ void phase_proj0(const KParams& p, int par, int E,
        const f16* WtB, int wt_str, const float* biasB, int bias_str,
        const float* MB, int m_str, const float* tvp, float* HstB) {
    int tid = threadIdx.x;
    int lane = tid & 63, w = tid >> 6;
    int wm = w >> 1, wn = w & 1;
    int l15 = lane & 15, lk = lane >> 4;
    int ntiles = 2*163*E;
    for (int idx = blockIdx.x; idx < ntiles; idx += gridDim.x) {
        int ob = idx & 1, rem = idx >> 1;
        int rt = rem % 163, e = rem / 163;
        const f16* Wt = WtB + (size_t)e*wt_str;
        const float* bias = biasB + (size_t)e*bias_str + 65280;
        const float* M = MB + (size_t)e*m_str;
        const f16* Dc = p.DP + (size_t)e*DP_E + (size_t)par*DP_B;
        f16* Dn = p.DP + (size_t)e*DP_E + (size_t)(par^1)*DP_B;
        f16* PTn = p.PT + (size_t)e*PT_E + (size_t)(par^1)*PT_B;
        float* ZR = p.ZR + (size_t)e*NB*64;
        float* Hs = HstB + (size_t)e*NB*64;
        int o0 = ob*64, r0 = rt*64;
        const f16* ap[2]; const f16* bp[2];
        #pragma unroll
        for (int a = 0; a < 2; a++) ap[a] = Wt + (size_t)(o0 + wm*32 + a*16 + l15)*352;
        #pragma unroll
        for (int bt = 0; bt < 2; bt++) bp[bt] = Dc + (size_t)(r0 + wn*32 + bt*16 + l15)*352;
        f32x4 acc[2][2] = {};
        #pragma unroll
        for (int k0 = 0; k0 < 352; k0 += 32) {
            f16x8 af[2], bf[2];
            #pragma unroll
            for (int a = 0; a < 2; a++) af[a] = *(const f16x8*)(ap[a] + k0 + lk*8);
            #pragma unroll
            for (int bt = 0; bt < 2; bt++) bf[bt] = *(const f16x8*)(bp[bt] + k0 + lk*8);
            #pragma unroll
            for (int a = 0; a < 2; a++)
                #pragma unroll
                for (int bt = 0; bt < 2; bt++)
                    acc[a][bt] = __builtin_amdgcn_mfma_f32_16x16x32_f16(af[a], bf[bt], acc[a][bt], 0,0,0);
        }
        #pragma unroll
        for (int bt = 0; bt < 2; bt++) {
            int r = r0 + wn*32 + bt*16 + l15;
            if (r < NB) {
                int n = r >> 5, b = r & 31;
                float tvb = tvp[b];
                #pragma unroll
                for (int a = 0; a < 2; a++) {
                    int oo = o0 + wm*32 + a*16 + lk*4;
                    float4 bs = *(const float4*)(bias + oo);
                    float4 ms = *(const float4*)(M + (size_t)n*128 + oo);
                    float p0 = acc[a][bt][0] + bs.x + tvb*ms.x;
                    float p1 = acc[a][bt][1] + bs.y + tvb*ms.y;
                    float p2 = acc[a][bt][2] + bs.z + tvb*ms.z;
                    float p3 = acc[a][bt][3] + bs.w + tvb*ms.w;
                    float s0 = 1.0f/(1.0f+expf(-p0)), s1 = 1.0f/(1.0f+expf(-p1));
                    float s2 = 1.0f/(1.0f+expf(-p2)), s3 = 1.0f/(1.0f+expf(-p3));
                    if (oo < 64) {
                        *(float4*)(ZR + (size_t)r*64 + oo) = make_float4(s0,s1,s2,s3);
                    } else {
                        int oh = oo - 64;
                        float4 h4 = *(const float4*)(Hs + (size_t)r*64 + oh);
                        float g0 = s0*h4.x, g1 = s1*h4.y, g2 = s2*h4.z, g3 = s3*h4.w;
                        st4h(Dn + (size_t)r*352 + 4 + oh, g0, g1, g2, g3);
                        size_t pb = (size_t)(b*68 + 4 + oh)*352 + n;
                        PTn[pb]       = (f16)g0;
                        PTn[pb + 352] = (f16)g1;
                        PTn[pb + 704] = (f16)g2;
                        PTn[pb + 1056]= (f16)g3;
                    }
                }
            }
        }
        if (ob == 0) {
            int row = tid >> 2, q = tid & 3;
            int r = r0 + row;
            if (r < NB) {
                f16 v = Dc[(size_t)r*352 + q];
                Dn[(size_t)r*352 + q] = v;
                PTn[(size_t)((r & 31)*68 + q)*352 + (r >> 5)] = v;
            }
        }
    }
}

__device__ void phase_proj1_enc(const KParams& p, int par, int t) {
    int tid = threadIdx.x;
    int lane = tid & 63, w = tid >> 6;
    int wm = w >> 1, wn = w & 1;
    int l15 = lane & 15, lk = lane >> 4;
    int ntiles = 163*2;
    for (int idx = blockIdx.x; idx < ntiles; idx += gridDim.x) {
        int rt = idx % 163, e = idx / 163;
        const f16* Wt = p.Wt + (size_t)e*WT_SET + 128*352;
        const float* bias = p.Weff + (size_t)e*WSET + 65408;
        const float* M = p.Mw + (size_t)e*M_SET + 325*128;
        const f16* Dc = p.DP + (size_t)e*DP_E + (size_t)par*DP_B;
        f16* Dn = p.DP + (size_t)e*DP_E + (size_t)(par^1)*DP_B;
        f16* PTn = p.PT + (size_t)e*PT_E + (size_t)(par^1)*PT_B;
        float* ZR = p.ZR + (size_t)e*NB*64;
        float* Hs = p.Henc + (size_t)e*NB*64;
        const float* tvv = p.tv + (size_t)t*32;
        int r0 = rt*64;
        const f16* ap[2]; const f16* bp[2];
        #pragma unroll
        for (int a = 0; a < 2; a++) ap[a] = Wt + (size_t)(wm*32 + a*16 + l15)*352;
        #pragma unroll
        for (int bt = 0; bt < 2; bt++) bp[bt] = Dc + (size_t)(r0 + wn*32 + bt*16 + l15)*352;
        f32x4 acc[2][2] = {};
        #pragma unroll
        for (int k0 = 0; k0 < 352; k0 += 32) {
            f16x8 af[2], bf[2];
            #pragma unroll
            for (int a = 0; a < 2; a++) af[a] = *(const f16x8*)(ap[a] + k0 + lk*8);
            #pragma unroll
            for (int bt = 0; bt < 2; bt++) bf[bt] = *(const f16x8*)(bp[bt] + k0 + lk*8);
            #pragma unroll
            for (int a = 0; a < 2; a++)
                #pragma unroll
                for (int bt = 0; bt < 2; bt++)
                    acc[a][bt] = __builtin_amdgcn_mfma_f32_16x16x32_f16(af[a], bf[bt], acc[a][bt], 0,0,0);
        }
        #pragma unroll
        for (int bt = 0; bt < 2; bt++) {
            int r = r0 + wn*32 + bt*16 + l15;
            if (r < NB) {
                int n = r >> 5, b = r & 31;
                float tvb = tvv[b];
                #pragma unroll
                for (int a = 0; a < 2; a++) {
                    int oo = wm*32 + a*16 + lk*4;
                    float4 bs = *(const float4*)(bias + oo);
                    float4 ms = *(const float4*)(M + (size_t)n*64 + oo);
                    float p0 = acc[a][bt][0] + bs.x + tvb*ms.x;
                    float p1 = acc[a][bt][1] + bs.y + tvb*ms.y;
                    float p2 = acc[a][bt][2] + bs.z + tvb*ms.z;
                    float p3 = acc[a][bt][3] + bs.w + tvb*ms.w;
                    float4 z4 = *(const float4*)(ZR + (size_t)r*64 + oo);
                    float4 h4 = *(const float4*)(Hs + (size_t)r*64 + oo);
                    float h0 = z4.x*h4.x + (1.0f - z4.x)*tanhf(p0);
                    float h1 = z4.y*h4.y + (1.0f - z4.y)*tanhf(p1);
                    float h2 = z4.z*h4.z + (1.0f - z4.z)*tanhf(p2);
                    float h3 = z4.w*h4.w + (1.0f - z4.w)*tanhf(p3);
                    *(float4*)(Hs + (size_t)r*64 + oo) = make_float4(h0,h1,h2,h3);
                    st4h(Dn + (size_t)r*352 + 4 + oo, h0, h1, h2, h3);
                    size_t pb = (size_t)(b*68 + 4 + oo)*352 + n;
                    PTn[pb]       = (f16)h0;
                    PTn[pb + 352] = (f16)h1;
                    PTn[pb + 704] = (f16)h2;
                    PTn[pb + 1056]= (f16)h3;
                }
            }
        }
        const f16* xn = nullptr;
        if (t < TENC-1) xn = p.xs + (size_t)(e*TENC + t + 1)*NB*4;
        if (xn) {
            int row = tid >> 2, q = tid & 3;
            int r = r0 + row;
            if (r < NB) {
                f16 v = (q < 3) ? xn[(size_t)r*4 + q] : (f16)0.0f;
                Dn[(size_t)r*352 + q] = v;
                PTn[(size_t)((r & 31)*68 + q)*352 + (r >> 5)] = v;
            }
        }
    }
}

__device__ void phase_proj1_dec(const KParams& p, int par, int t, f16* smem) {
    int tid = threadIdx.x;
    int lane = tid & 63, w = tid >> 6;
    int wm = w >> 1, wn = w & 1;
    int l15 = lane & 15, lk = lane >> 4;
    const f16* Wt = p.Wt + 2*WT_SET + 128*352;
    const float* bias = p.Weff + 2*WSET + 65408;
    const float* M = p.Mw + 2*M_SET + 325*128;
    const f16* Dc = p.DP + (size_t)par*DP_B;
    f16* Dn = p.DP + (size_t)(par^1)*DP_B;
    f16* PTn = p.PT + (size_t)(par^1)*PT_B;
    const float* tvv = p.tv + (size_t)(6 + t)*32;
    for (int idx = blockIdx.x; idx < 163; idx += gridDim.x) {
        int r0 = idx*64;
        const f16* ap[2]; const f16* bp[2];
        #pragma unroll
        for (int a = 0; a < 2; a++) ap[a] = Wt + (size_t)(wm*32 + a*16 + l15)*352;
        #pragma unroll
        for (int bt = 0; bt < 2; bt++) bp[bt] = Dc + (size_t)(r0 + wn*32 + bt*16 + l15)*352;
        f32x4 acc[2][2] = {};
        #pragma unroll
        for (int k0 = 0; k0 < 352; k0 += 32) {
            f16x8 af[2], bf[2];
            #pragma unroll
            for (int a = 0; a < 2; a++) af[a] = *(const f16x8*)(ap[a] + k0 + lk*8);
            #pragma unroll
            for (int bt = 0; bt < 2; bt++) bf[bt] = *(const f16x8*)(bp[bt] + k0 + lk*8);
            #pragma unroll
            for (int a = 0; a < 2; a++)
                #pragma unroll
                for (int bt = 0; bt < 2; bt++)
                    acc[a][bt] = __builtin_amdgcn_mfma_f32_16x16x32_f16(af[a], bf[bt], acc[a][bt], 0,0,0);
        }
        #pragma unroll
        for (int bt = 0; bt < 2; bt++) {
            int r = r0 + wn*32 + bt*16 + l15;
            int rl = wn*32 + bt*16 + l15;
            if (r < NB) {
                int n = r >> 5, b = r & 31;
                float tvb = tvv[b];
                #pragma unroll
                for (int a = 0; a < 2; a++) {
                    int oo = wm*32 + a*16 + lk*4;
                    float4 bs = *(const float4*)(bias + oo);
                    float4 ms = *(const float4*)(M + (size_t)n*64 + oo);
                    float p0 = acc[a][bt][0] + bs.x + tvb*ms.x;
                    float p1 = acc[a][bt][1] + bs.y + tvb*ms.y;
                    float p2 = acc[a][bt][2] + bs.z + tvb*ms.z;
                    float p3 = acc[a][bt][3] + bs.w + tvb*ms.w;
                    float4 z4 = *(const float4*)(p.ZR + (size_t)r*64 + oo);
                    float4 h4 = *(const float4*)(p.Hdec + (size_t)r*64 + oo);
                    float h0 = z4.x*h4.x + (1.0f - z4.x)*tanhf(p0);
                    float h1 = z4.y*h4.y + (1.0f - z4.y)*tanhf(p1);
                    float h2 = z4.z*h4.z + (1.0f - z4.z)*tanhf(p2);
                    float h3 = z4.w*h4.w + (1.0f - z4.w)*tanhf(p3);
                    *(float4*)(p.Hdec + (size_t)r*64 + oo) = make_float4(h0,h1,h2,h3);
                    st4h(Dn + (size_t)r*352 + 4 + oo, h0, h1, h2, h3);
                    size_t pb = (size_t)(b*68 + 4 + oo)*352 + n;
                    PTn[pb]       = (f16)h0;
                    PTn[pb + 352] = (f16)h1;
                    PTn[pb + 704] = (f16)h2;
                    PTn[pb + 1056]= (f16)h3;
                    st4h(smem + rl*68 + oo, h0, h1, h2, h3);
                }
            }
        }
        __syncthreads();
        for (int q = tid; q < 192; q += 256) {
            int row = q / 3, o = q - row*3;
            int r = r0 + row;
            if (r < NB) {
                float a = p.bfc[o];
                #pragma unroll 8
                for (int k = 0; k < 64; k++)
                    a = fmaf((float)smem[row*68 + k], p.Wfc[k*3 + o], a);
                p.ys[(size_t)t*NB*3 + (size_t)r*3 + o] = a;
                Dn[(size_t)r*352 + o] = (f16)a;
                PTn[(size_t)((r & 31)*68 + o)*352 + (r >> 5)] = (f16)a;
            }
        }
        __syncthreads();
    }
}

__device__ void phase_fuse(const KParams& p, f16* smem) {
    int tid = threadIdx.x;
    int lane = tid & 63, wave = tid >> 6;
    int wm = wave >> 1, wn = wave & 1;
    int l15 = lane & 15, lk = lane >> 4;
    const float* H1 = p.Henc;
    const float* H2 = p.Henc + (size_t)NB*64;
    unsigned* La = (unsigned*)smem;
    f16* Dn = p.DP;
    f16* PTn = p.PT;
    for (int idx = blockIdx.x; idx < 163; idx += gridDim.x) {
        int r0 = idx*64;
        for (int l = tid; l < 64*64; l += 256) {
            int i = l >> 6, k = l & 63;
            int r = r0 + i;
            unsigned val = 0;
            if (r < NB) {
                int n = r >> 5;
                float h1 = H1[(size_t)r*64 + k], h2 = H2[(size_t)r*64 + k];
                float s = h1 + h2;
                val = pk2(s*p.wL[n*64+k] + 2.0f*p.bL[n*64+k],
                          s*p.wH[n*64+k] + 2.0f*p.bH[n*64+k]);
            }
            La[i*132 + k] = val;
        }
        for (int l = tid; l < 64*32; l += 256) {
            int i = l >> 5, kp = l & 31;
            int r = r0 + i;
            unsigned v1 = 0, v2 = 0;
            if (r < NB) {
                float2 a = *(const float2*)(H1 + (size_t)r*64 + 2*kp);
                float2 b = *(const float2*)(H2 + (size_t)r*64 + 2*kp);
                v1 = pk2(a.x, a.y);
                v2 = pk2(b.x, b.y);
            }
            La[i*132 + 64 + kp] = v1;
            La[i*132 + 96 + kp] = v2;
        }
        __syncthreads();
        f32x4 acc[2][2] = {};
        for (int k0 = 0; k0 < 256; k0 += 32) {
            f16x8 afr[2], bfr[2];
            #pragma unroll
            for (int a = 0; a < 2; a++)
                afr[a] = ld8_lds(smem + (wm*32 + a*16 + l15)*264 + k0 + lk*8);
            #pragma unroll
            for (int b = 0; b < 2; b++)
                bfr[b] = *(const f16x8*)(p.Wfuse + (size_t)(wn*32 + b*16 + l15)*256 + k0 + lk*8);
            #pragma unroll
            for (int a = 0; a < 2; a++)
                #pragma unroll
                for (int b = 0; b < 2; b++)
                    acc[a][b] = __builtin_amdgcn_mfma_f32_16x16x32_f16(afr[a], bfr[b], acc[a][b], 0,0,0);
        }
        #pragma unroll
        for (int a = 0; a < 2; a++) {
            #pragma unroll
            for (int b = 0; b < 2; b++) {
                int o = wn*32 + b*16 + l15;
                float bo = 0.3f*p.bcam[o] + 0.7f*p.bagg[o];
                #pragma unroll
                for (int rr = 0; rr < 4; rr++) {
                    int r = r0 + wm*32 + a*16 + lk*4 + rr;
                    if (r >= NB) continue;
                    float val = acc[a][b][rr] + bo;
                    p.Hdec[(size_t)r*64 + o] = val;
                    Dn[(size_t)r*352 + 4 + o] = (f16)val;
                    PTn[(size_t)((r & 31)*68 + 4 + o)*352 + (r >> 5)] = (f16)val;
                }
            }
        }
        {
            int r = r0 + (tid >> 2), q = tid & 3;
            if (r < NB) {
                Dn[(size_t)r*352 + q] = (f16)0.0f;
                PTn[(size_t)((r & 31)*68 + q)*352 + (r >> 5)] = (f16)0.0f;
            }
        }
        __syncthreads();
    }
}

__device__ void phase_out(const KParams& p) {
    for (int idx = blockIdx.x*256 + threadIdx.x; idx < BB*3*NN*12; idx += gridDim.x*256) {
        int l = idx % 12;
        int n = (idx / 12) % NN;
        int o = (idx / (12*NN)) % 3;
        int b = idx / (12*NN*3);
        int q = o*12 + l;
        int t = q / 3, c = q % 3;
        p.out[idx] = p.ys[((size_t)t*NB + n*BB + b)*3 + c];
    }
}

// ---------------- cooperative main ----------------
__global__ __launch_bounds__(256, 4) void k_main(KParams p) {
    cg::grid_group grid = cg::this_grid();
    __shared__ f16 smem[64*264];
    int par = 0;
    for (int t = 0; t < TENC; t++) {
        phase_diff(p, par, 2); grid.sync();
        phase_proj0(p, par, 2, p.Wt, WT_SET, p.Weff, WSET, p.Mw, M_SET,
                    p.tv + (size_t)t*32, p.Henc);
        grid.sync();
        par ^= 1;
        phase_diff(p, par, 2); grid.sync();
        phase_proj1_enc(p, par, t); grid.sync();
        par ^= 1;
    }
    phase_fuse(p, smem); grid.sync();
    for (int t = 0; t < TDEC; t++) {
        phase_diff(p, par, 1); grid.sync();
        phase_proj0(p, par, 1, p.Wt + 2*WT_SET, 0, p.Weff + 2*WSET, 0,
                    p.Mw + 2*M_SET, 0, p.tv + (size_t)(6 + t)*32, p.Hdec);
        grid.sync();
        par ^= 1;
        phase_diff(p, par, 1); grid.sync();
        phase_proj1_dec(p, par, t, smem); grid.sync();
        par ^= 1;
    }
    phase_out(p);
}

// ---------------- fallback wrappers (identical math, split launches) ----------
__global__ __launch_bounds__(256) void g_diff(KParams p, int par, int E) { phase_diff(p, par, E); }
__global__ __launch_bounds__(256) void g_proj0e(KParams p, int par, int t) {
    phase_proj0(p, par, 2, p.Wt, WT_SET, p.Weff, WSET, p.Mw, M_SET,
                p.tv + (size_t)t*32, p.Henc);
}
__global__ __launch_bounds__(256) void g_proj0d(KParams p, int par, int t) {
    phase_proj0(p, par, 1, p.Wt + 2*WT_SET, 0, p.Weff + 2*WSET, 0,
                p.Mw + 2*M_SET, 0, p.tv + (size_t)(6 + t)*32, p.Hdec);
}
__global__ __launch_bounds__(256) void g_proj1e(KParams p, int par, int t) { phase_proj1_enc(p, par, t); }
__global__ __launch_bounds__(256) void g_proj1d(KParams p, int par, int t) {
    __shared__ f16 smem[64*68];
    phase_proj1_dec(p, par, t, smem);
}
__global__ __launch_bounds__(256) void g_fuse(KParams p) {
    __shared__ f16 smem[64*264];
    phase_fuse(p, smem);
}
__global__ __launch_bounds__(256) void g_out(KParams p) { phase_out(p); }

// ---------------- host ----------------
extern "C" void kernel_launch(void* const* d_in, const int* in_sizes, int n_in,
                              void* d_out, int out_size, void* d_ws, size_t ws_size,
                              hipStream_t stream) {
    const float* x      = (const float*)d_in[0];
    const float* st     = (const float*)d_in[1];
    const float* adj    = (const float*)d_in[2];
    const float* P      = (const float*)d_in[3];
    const float* H1_0   = (const float*)d_in[4];
    const float* H2_0   = (const float*)d_in[6];
    const float* W_encD = (const float*)d_in[8];
    const float* b_encD = (const float*)d_in[9];
    const float* W_encAD= (const float*)d_in[10];
    const float* b_encAD= (const float*)d_in[11];
    const float* W_dec  = (const float*)d_in[12];
    const float* b_dec  = (const float*)d_in[13];
    const float* W_fc   = (const float*)d_in[14];
    const float* b_fc   = (const float*)d_in[15];
    const float* W_aggH = (const float*)d_in[16];
    const float* b_aggH = (const float*)d_in[17];
    const float* W_camH = (const float*)d_in[20];
    const float* b_camH = (const float*)d_in[21];
    const float* wL     = (const float*)d_in[24];
    const float* bL     = (const float*)d_in[25];
    const float* wH     = (const float*)d_in[26];
    const float* bH     = (const float*)d_in[27];

    float* ws   = (float*)d_ws;
    float* G    = ws + OFF_G;
    float* rs   = ws + OFF_RS;
    float* cs   = rs + NN;
    float* rv   = ws + OFF_RV;
    float* Weff = ws + OFF_WEFF;
    f16*   Wt   = (f16*)(ws + OFF_WT);
    f16*   G16  = (f16*)(ws + OFF_G16);
    float* Mw   = ws + OFF_M;
    f16*   Wf   = (f16*)(ws + OFF_WF);
    float* tv   = ws + OFF_TV;
    f16*   xs   = (f16*)(ws + OFF_XS);
    f16*   PT   = (f16*)(ws + OFF_PT);
    f16*   DP   = (f16*)(ws + OFF_DP);
    float* ZR   = ws + OFF_ZR;
    float* G2   = ZR;
    float* Henc = ws + OFF_HENC;
    float* Hdec = ws + OFF_HDEC;
    float* ys   = ws + OFF_YS;

    // ---- prep ----
    k_sums<<<NN, 64, 0, stream>>>(adj, rs, cs);
    k_buildG<<<(NN*NN + 255)/256, 256, 0, stream>>>(adj, P, rs, cs, G);
    k_gg<<<dim3(11,11,2), 256, 0, stream>>>(G, G2);
    k_g16<<<(4*G16_MAT + 255)/256, 256, 0, stream>>>(G, G2, G16);
    k_rowsum<<<650, 64, 0, stream>>>(G, G2, rv);
    k_weff3<<<dim3(255,3), 256, 0, stream>>>(W_encD, b_encD, W_encAD, b_encAD,
                                             W_dec, b_dec, Weff);
    k_wt3<<<dim3((192*352 + 255)/256, 3), 256, 0, stream>>>(Weff, Wt);
    k_M3<<<dim3((325*192 + 255)/256, 3), 256, 0, stream>>>(Weff, rv, Mw);
    k_wfuse<<<64, 256, 0, stream>>>(W_camH, W_aggH, Wf);
    k_tv<<<3, 256, 0, stream>>>(st, tv);
    k_xs16<<<(2*TENC*NB*4 + 255)/256, 256, 0, stream>>>(x, xs);
    k_initH<<<(2*NB*64 + 255)/256, 256, 0, stream>>>(H1_0, H2_0, Henc);
    k_initDP<<<(2*NB*92 + 255)/256, 256, 0, stream>>>(xs, H1_0, H2_0, DP);
    k_initPT<<<(2*2176*352 + 255)/256, 256, 0, stream>>>(xs, H1_0, H2_0, PT);

    KParams prm;
    prm.G16 = G16; prm.PT = PT; prm.DP = DP;
    prm.Wt = Wt; prm.Weff = Weff; prm.Mw = Mw; prm.tv = tv;
    prm.ZR = ZR; prm.Henc = Henc; prm.Hdec = Hdec;
    prm.xs = xs;
    prm.wL = wL; prm.bL = bL; prm.wH = wH; prm.bH = bH;
    prm.bcam = b_camH; prm.bagg = b_aggH; prm.Wfuse = Wf;
    prm.Wfc = W_fc; prm.bfc = b_fc;
    prm.ys = ys; prm.out = (float*)d_out;

    // ---- try cooperative persistent kernel with occupancy-sized grid ----
    hipError_t cerr = hipErrorUnknown;
    int occ = 0;
    hipError_t oerr = hipOccupancyMaxActiveBlocksPerMultiprocessor(
        &occ, reinterpret_cast<const void*>(k_main), 256, 0);
    if (oerr == hipSuccess && occ > 0) {
        int cus = 0;
        if (hipDeviceGetAttribute(&cus, hipDeviceAttributeMultiprocessorCount, 0)
                != hipSuccess || cus <= 0)
            cus = 256;
        long long maxb = (long long)occ * cus;
        int nblk = (int)(maxb < 1024 ? maxb : 1024);
        if (nblk > 0) {
            void* kargs[] = { &prm };
            cerr = hipLaunchCooperativeKernel(reinterpret_cast<void*>(k_main),
                                              dim3(nblk), dim3(256), kargs, 0, stream);
        }
    }

    if (cerr != hipSuccess) {
        // ---- fallback: identical math as split launches (R6 parity) ----
        int par = 0;
        for (int t = 0; t < TENC; t++) {
            g_diff<<<1428, 256, 0, stream>>>(prm, par, 2);
            g_proj0e<<<652, 256, 0, stream>>>(prm, par, t);
            par ^= 1;
            g_diff<<<1428, 256, 0, stream>>>(prm, par, 2);
            g_proj1e<<<326, 256, 0, stream>>>(prm, par, t);
            par ^= 1;
        }
        g_fuse<<<163, 256, 0, stream>>>(prm);
        for (int t = 0; t < TDEC; t++) {
            g_diff<<<714, 256, 0, stream>>>(prm, par, 1);
            g_proj0d<<<326, 256, 0, stream>>>(prm, par, t);
            par ^= 1;
            g_diff<<<714, 256, 0, stream>>>(prm, par, 1);
            g_proj1d<<<163, 256, 0, stream>>>(prm, par, t);
            par ^= 1;
        }
        g_out<<<458, 256, 0, stream>>>(prm);
    }
}

// Round 10
// 1357.819 us; speedup vs baseline: 4.6942x; 4.6942x over previous
//
#include <hip/hip_runtime.h>
#include <math.h>

#define NN 325
#define BB 32
#define NB (NN*BB)            // 10400
#define TENC 6
#define TDEC 12
#define WSET 65472            // fp32 Weff: Wzr(340x128)+Wc(340x64)+bzr(128)+bc(64)
#define WT_SET (192*352)      // f16 transposed weights per set
#define M_SET (325*192)       // Mzr[325][128] + Mc[325][64]
#define G16_MAT (384*352)
#define PT_B 765952ull        // 2176*352 f16 per buf
#define PT_E 1531904ull
#define DP_B 3660800ull       // 10400*352 f16 per buf
#define DP_E 7321600ull

typedef _Float16 f16;
typedef f16 f16x4 __attribute__((ext_vector_type(4)));
typedef f16 f16x8 __attribute__((ext_vector_type(8)));
typedef float f32x4 __attribute__((ext_vector_type(4)));

static constexpr float ALPHA = 0.05f;
static constexpr float BETA  = 0.95f;
static constexpr float GAMMA = 0.95f;
static constexpr float ISQ2  = 0.7071067811865476f;

// ---------------- workspace offsets (floats) ----------------
static constexpr size_t OFF_G    = 0;
static constexpr size_t OFF_RS   = OFF_G + 2ull*NN*NN;
static constexpr size_t OFF_RV   = OFF_RS + 650;
static constexpr size_t OFF_WEFF = OFF_RV + 1300;
static constexpr size_t OFF_WT   = OFF_WEFF + 3ull*WSET;
static constexpr size_t OFF_G16  = OFF_WT + (3ull*WT_SET)/2;
static constexpr size_t OFF_M    = OFF_G16 + (4ull*G16_MAT)/2;
static constexpr size_t OFF_WF   = OFF_M + 3ull*M_SET;          // 64*256 f16 -> 8192
static constexpr size_t OFF_TV   = OFF_WF + 8192;               // 576
static constexpr size_t OFF_XS   = OFF_TV + 576;
static constexpr size_t OFF_PT   = OFF_XS + (2ull*TENC*NB*4)/2;
static constexpr size_t OFF_DP   = OFF_PT + (2ull*PT_E)/2;
static constexpr size_t OFF_ZR   = OFF_DP + (2ull*DP_E)/2;      // 2*NB*64 fp32 (G2 alias)
static constexpr size_t OFF_HENC = OFF_ZR + 2ull*NB*64;
static constexpr size_t OFF_HDEC = OFF_HENC + 2ull*NB*64;

__device__ inline unsigned pk2(float a, float b) {
    union { f16 h[2]; unsigned u; } x;
    x.h[0] = (f16)a; x.h[1] = (f16)b; return x.u;
}
__device__ inline void st4h(f16* p, float a, float b, float c, float d) {
    f16x4 v; v[0]=(f16)a; v[1]=(f16)b; v[2]=(f16)c; v[3]=(f16)d;
    *(f16x4*)p = v;
}
__device__ inline f16x8 ld8_lds(const f16* p) {
    f16x4 lo = *(const f16x4*)p;
    f16x4 hi = *(const f16x4*)(p + 4);
    f16x8 r;
    r[0]=lo[0]; r[1]=lo[1]; r[2]=lo[2]; r[3]=lo[3];
    r[4]=hi[0]; r[5]=hi[1]; r[6]=hi[2]; r[7]=hi[3];
    return r;
}

// ---------------- prep ----------------
__global__ void k_sums(const float* __restrict__ adj, float* rs, float* cs) {
    int v = blockIdx.x; int t = threadIdx.x;
    float sr = 0.f, sc = 0.f;
    for (int w = t; w < NN; w += 64) { sr += adj[v*NN + w]; sc += adj[w*NN + v]; }
    for (int o = 32; o > 0; o >>= 1) { sr += __shfl_down(sr, o); sc += __shfl_down(sc, o); }
    if (t == 0) { rs[v] = sr + 1.0f; cs[v] = sc + 1.0f; }
}

__global__ void k_buildG(const float* __restrict__ adj, const float* __restrict__ P,
                         const float* __restrict__ rs, const float* __restrict__ cs,
                         float* __restrict__ G) {
    int idx = blockIdx.x*256 + threadIdx.x;
    if (idx >= NN*NN) return;
    int w = idx / NN, v = idx % NN;
    float d = (v == w) ? 1.0f : 0.0f;
    float a1  = (adj[v*NN + w] + d) / rs[v];
    float a1t = (adj[w*NN + v] + d) / cs[v];
    float p = P[v*NN + w];
    G[idx]         = BETA*a1  + GAMMA*p;
    G[NN*NN + idx] = BETA*a1t + GAMMA*p;
}

__global__ __launch_bounds__(256) void k_gg(const float* __restrict__ G, float* __restrict__ G2) {
    int g = blockIdx.z;
    const float* A = G + (size_t)g*NN*NN;
    float* C = G2 + (size_t)g*NN*NN;
    int n0 = blockIdx.y*32, j0 = blockIdx.x*32;
    int tx = threadIdx.x & 31, ty = threadIdx.x >> 5;
    __shared__ float As[32][33];
    __shared__ float Bs[32][33];
    float acc[4] = {};
    for (int k0 = 0; k0 < NN; k0 += 32) {
        for (int l = threadIdx.x; l < 32*32; l += 256) {
            int i = l >> 5, kk = l & 31;
            int n = n0 + i, k = k0 + kk;
            As[i][kk] = (n < NN && k < NN) ? A[(size_t)n*NN + k] : 0.0f;
            int j = j0 + kk;
            Bs[i][kk] = (k0 + i < NN && j < NN) ? A[(size_t)(k0+i)*NN + j] : 0.0f;
        }
        __syncthreads();
        #pragma unroll 8
        for (int kk = 0; kk < 32; kk++) {
            float bv = Bs[kk][tx];
            #pragma unroll
            for (int i = 0; i < 4; i++) acc[i] = fmaf(As[ty + 8*i][kk], bv, acc[i]);
        }
        __syncthreads();
    }
    #pragma unroll
    for (int i = 0; i < 4; i++) {
        int n = n0 + ty + 8*i, j = j0 + tx;
        if (n < NN && j < NN) C[(size_t)n*NN + j] = acc[i];
    }
}

__global__ void k_g16(const float* __restrict__ G, const float* __restrict__ G2,
                      f16* __restrict__ G16) {
    int idx = blockIdx.x*256 + threadIdx.x;
    if (idx >= 4*G16_MAT) return;
    int m = idx / G16_MAT;
    int rem = idx - m*G16_MAT;
    int n = rem / 352, v = rem - n*352;
    int g = m >> 1, s = m & 1;
    float val = 0.0f;
    if (n < NN && v < NN) {
        float gv = G[(size_t)g*NN*NN + n*NN + v];
        float d = (n == v) ? ALPHA : 0.0f;
        val = (s == 0) ? (gv + d)
                       : (G2[(size_t)g*NN*NN + n*NN + v] + ALPHA*gv + d);
    }
    G16[idx] = (f16)val;
}

__global__ void k_rowsum(const float* __restrict__ G, const float* __restrict__ G2,
                         float* __restrict__ rv) {
    int row = blockIdx.x;
    int g = row / NN, n = row - g*NN;
    int t = threadIdx.x;
    float s1 = 0.f, s2 = 0.f;
    for (int v = t; v < NN; v += 64) {
        s1 += G[(size_t)g*NN*NN + n*NN + v];
        s2 += G2[(size_t)g*NN*NN + n*NN + v];
    }
    for (int o = 32; o > 0; o >>= 1) { s1 += __shfl_down(s1, o); s2 += __shfl_down(s2, o); }
    if (t == 0) {
        rv[(g*2 + 0)*NN + n] = ALPHA + s1;
        rv[(g*2 + 1)*NN + n] = ALPHA + ALPHA*s1 + s2;
    }
}

__global__ void k_weff3(const float* __restrict__ W0, const float* __restrict__ b0,
                        const float* __restrict__ W1, const float* __restrict__ b1,
                        const float* __restrict__ W2, const float* __restrict__ b2,
                        float* __restrict__ WeffAll) {
    int s = blockIdx.y;
    const float* W = (s == 0) ? W0 : (s == 1) ? W1 : W2;
    const float* b = (s == 0) ? b0 : (s == 1) ? b1 : b2;
    float* Wset = WeffAll + (size_t)s*WSET;
    float* Wzr = Wset;
    float* Wc  = Wset + 43520;
    float* bzr = Wset + 65280;
    float* bc  = Wset + 65408;
    int tid = blockIdx.x*256 + threadIdx.x;
    if (tid < 340*192) {
        int k = tid / 192, col = tid % 192;
        int g = col >> 6, oo = col & 63;
        const float* Wa = W + (2*g)*204*64;
        const float* Wb = W + (2*g+1)*204*64;
        float val;
        if (k < 68)       val = Wa[k*64+oo] + Wb[k*64+oo];
        else if (k < 204) val = Wa[k*64+oo];
        else              val = Wb[(k-136)*64+oo];
        if (g < 2) Wzr[k*128 + g*64 + oo] = val;
        else       Wc[k*64 + oo] = val;
    }
    if (blockIdx.x == 0 && threadIdx.x < 192) {
        int col = threadIdx.x, g = col >> 6, oo = col & 63;
        float bv = b[(2*g)*64+oo] + b[(2*g+1)*64+oo];
        if (g < 2) bzr[col] = bv; else bc[oo] = bv;
    }
}

__global__ void k_wt3(const float* __restrict__ WeffAll, f16* __restrict__ WtAll) {
    int s = blockIdx.y;
    const float* Weff = WeffAll + (size_t)s*WSET;
    f16* Wt = WtAll + (size_t)s*WT_SET;
    int idx = blockIdx.x*256 + threadIdx.x;
    if (idx >= 192*352) return;
    int o = idx / 352, k = idx - o*352;
    float v = 0.0f;
    if (k < 340) {
        int p = k / 68, c = k - p*68;
        if (c != 3) v = (o < 128) ? Weff[k*128 + o] : Weff[43520 + k*64 + (o - 128)];
    }
    Wt[idx] = (f16)v;
}

__global__ void k_M3(const float* __restrict__ WeffAll, const float* __restrict__ rv,
                     float* __restrict__ MAll) {
    int s = blockIdx.y;
    const float* Weff = WeffAll + (size_t)s*WSET;
    float* M = MAll + (size_t)s*M_SET;
    int idx = blockIdx.x*256 + threadIdx.x;
    if (idx >= 325*192) return;
    int n = idx / 192, q = idx - n*192;
    float acc;
    if (q < 128) {
        int o = q;
        acc = Weff[3*128 + o];
        #pragma unroll
        for (int p = 1; p <= 4; p++)
            acc += rv[(p-1)*NN + n] * Weff[(p*68 + 3)*128 + o];
        M[(size_t)n*128 + o] = acc;
    } else {
        int o = q - 128;
        acc = Weff[43520 + 3*64 + o];
        #pragma unroll
        for (int p = 1; p <= 4; p++)
            acc += rv[(p-1)*NN + n] * Weff[43520 + (p*68 + 3)*64 + o];
        M[325*128 + (size_t)n*64 + o] = acc;
    }
}

__global__ void k_wfuse(const float* __restrict__ Wcam, const float* __restrict__ Wagg,
                        f16* __restrict__ Wf) {
    int idx = blockIdx.x*256 + threadIdx.x;
    if (idx >= 64*256) return;
    int o = idx >> 8, k = idx & 255;
    float v = (k < 128) ? 0.3f*Wcam[(size_t)k*64 + o]
                        : 0.7f*Wagg[(size_t)(k-128)*64 + o];
    Wf[(size_t)o*256 + k] = (f16)v;
}

__global__ void k_tv(const float* __restrict__ st, float* __restrict__ tv) {
    int idx = blockIdx.x*256 + threadIdx.x;
    if (idx >= 18*32) return;
    int b = idx & 31, t = idx >> 5;
    float v;
    if (t < 6) {
        float hour   = (st[b*48 + 24 + 2*t] + 0.5f) * 23.0f;
        float minute = (st[b*48 + 36 + 2*t] + 0.5f) * 59.0f;
        v = floorf((hour*60.0f + minute) / 5.0f);
    } else {
        int td = t - 6;
        v = floorf((st[b*48 + 24 + td] + 0.5f) * 6.0f);
    }
    tv[idx] = v;
}

__global__ void k_xs16(const float* __restrict__ x, f16* __restrict__ xs) {
    int idx = blockIdx.x*256 + threadIdx.x;
    if (idx >= 2*TENC*NB*4) return;
    int c = idx & 3;
    int r = (idx >> 2) % NB;
    int t = (idx / (4*NB)) % TENC;
    int e = idx / (4*NB*TENC);
    int n = r / BB, b = r % BB;
    float val = 0.0f;
    if (c < 3) {
        float xe = x[((b*3 + c)*NN + n)*12 + 2*t];
        float xo = x[((b*3 + c)*NN + n)*12 + 2*t + 1];
        val = (e == 0) ? (xe - xo)*ISQ2 : (xe + xo)*ISQ2;
    }
    xs[idx] = (f16)val;
}

__global__ void k_initH(const float* __restrict__ H1_0, const float* __restrict__ H2_0,
                        float* __restrict__ Henc) {
    int idx = blockIdx.x*256 + threadIdx.x;
    if (idx >= 2*NB*64) return;
    int k = idx & 63;
    int r = (idx >> 6) % NB;
    int e = idx / (NB*64);
    int n = r / BB, b = r % BB;
    const float* src = e ? H2_0 : H1_0;
    Henc[idx] = src[((size_t)b*NN + n)*64 + k];
}

__global__ void k_initDP(const f16* __restrict__ xs, const float* __restrict__ H1_0,
                         const float* __restrict__ H2_0, f16* __restrict__ DP) {
    int idx = blockIdx.x*256 + threadIdx.x;
    if (idx >= 2*NB*92) return;
    int cc = idx % 92;
    int r = (idx / 92) % NB;
    int e = idx / (92*NB);
    int n = r >> 5, b = r & 31;
    f16* D0 = DP + (size_t)e*DP_E;
    if (cc < 68) {
        f16 v;
        if (cc < 3)       v = xs[(size_t)e*TENC*NB*4 + (size_t)r*4 + cc];
        else if (cc == 3) v = (f16)0.0f;
        else {
            const float* h0 = e ? H2_0 : H1_0;
            v = (f16)h0[((size_t)b*NN + n)*64 + (cc-4)];
        }
        D0[(size_t)r*352 + cc] = v;
    } else if (cc < 80) {
        D0[(size_t)r*352 + 340 + (cc-68)] = (f16)0.0f;
    } else {
        D0[DP_B + (size_t)r*352 + 340 + (cc-80)] = (f16)0.0f;
    }
}

__global__ void k_initPT(const f16* __restrict__ xs, const float* __restrict__ H1_0,
                         const float* __restrict__ H2_0, f16* __restrict__ PTb) {
    int idx = blockIdx.x*256 + threadIdx.x;
    if (idx >= 2*2176*352) return;
    int v = idx % 352;
    int j = (idx / 352) % 2176;
    int e = idx / (352*2176);
    f16* P0 = PTb + (size_t)e*PT_E;
    if (v >= NN) {
        P0[(size_t)j*352 + v] = (f16)0.0f;
        P0[PT_B + (size_t)j*352 + v] = (f16)0.0f;
        return;
    }
    int b = j / 68, c = j - b*68;
    f16 val;
    if (c < 3)       val = xs[(size_t)e*TENC*NB*4 + (size_t)(v*32+b)*4 + c];
    else if (c == 3) val = (f16)0.0f;
    else {
        const float* h0 = e ? H2_0 : H1_0;
        val = (f16)h0[((size_t)b*NN + v)*64 + (c-4)];
    }
    P0[(size_t)j*352 + v] = val;
}

// ================= phases =================
struct KParams {
    const f16* G16;
    f16* PT;
    f16* DP;
    const f16* Wt;
    const float* Weff;
    const float* Mw;
    const float* tv;
    float* ZR;
    float* Henc;
    float* Hdec;
    const f16* xs;
    const float* wL; const float* bL; const float* wH; const float* bH;
    const float* bcam; const float* bagg;
    const f16* Wfuse;
    const float* Wfc; const float* bfc;
    float* out;
};

__device__ void phase_diff(const KParams& p, int par, int E) {
    int tid = threadIdx.x;
    int lane = tid & 63, w = tid >> 6;
    int wm = w >> 1, wn = w & 1;
    int l15 = lane & 15, lk = lane >> 4;
    int ntiles = 34*21*E;
    for (int idx = blockIdx.x; idx < ntiles; idx += gridDim.x) {
        int jt = idx % 34, rem = idx / 34;
        int Rt = rem % 21, e = rem / 21;
        const f16* X = p.PT + (size_t)e*PT_E + (size_t)par*PT_B;
        f16* D = p.DP + (size_t)e*DP_E + (size_t)par*DP_B;
        int j0 = jt*64, R0 = Rt*64;
        const f16* ap[2];
        #pragma unroll
        for (int a = 0; a < 2; a++)
            ap[a] = X + (size_t)(j0 + wm*32 + a*16 + l15)*352;
        const f16* bp[2]; int mv[2], nv[2];
        #pragma unroll
        for (int bt = 0; bt < 2; bt++) {
            int R = R0 + wn*32 + bt*16 + l15;
            int ok = (R < 1300);
            int Rc = ok ? R : 0;
            int m = Rc / 325, n = Rc - m*325;
            mv[bt] = ok ? m : -1; nv[bt] = n;
            bp[bt] = p.G16 + (size_t)m*G16_MAT + (size_t)n*352;
        }
        f32x4 acc[2][2] = {};
        #pragma unroll
        for (int k0 = 0; k0 < 352; k0 += 32) {
            f16x8 af[2], bf[2];
            #pragma unroll
            for (int a = 0; a < 2; a++) af[a] = *(const f16x8*)(ap[a] + k0 + lk*8);
            #pragma unroll
            for (int bt = 0; bt < 2; bt++) bf[bt] = *(const f16x8*)(bp[bt] + k0 + lk*8);
            #pragma unroll
            for (int a = 0; a < 2; a++)
                #pragma unroll
                for (int bt = 0; bt < 2; bt++)
                    acc[a][bt] = __builtin_amdgcn_mfma_f32_16x16x32_f16(af[a], bf[bt], acc[a][bt], 0,0,0);
        }
        #pragma unroll
        for (int bt = 0; bt < 2; bt++) {
            if (mv[bt] < 0) continue;
            int m = mv[bt], n = nv[bt];
            #pragma unroll
            for (int a = 0; a < 2; a++) {
                int jb = j0 + wm*32 + a*16 + lk*4;
                int b = jb / 68, c = jb - b*68;
                f16* dst = D + (size_t)(n*32 + b)*352 + (m+1)*68 + c;
                st4h(dst, acc[a][bt][0], acc[a][bt][1], acc[a][bt][2], acc[a][bt][3]);
            }
        }
    }
}

__device__ void phase_proj0(const KParams& p, int par, int E,
        const f16* WtB, int wt_str, const float* biasB, int bias_str,
        const float* MB, int m_str, const float* tvp, float* HstB) {
    int tid = threadIdx.x;
    int lane = tid & 63, w = tid >> 6;
    int wm = w >> 1, wn = w & 1;
    int l15 = lane & 15, lk = lane >> 4;
    int ntiles = 2*163*E;
    for (int idx = blockIdx.x; idx < ntiles; idx += gridDim.x) {
        int ob = idx & 1, rem = idx >> 1;
        int rt = rem % 163, e = rem / 163;
        const f16* Wt = WtB + (size_t)e*wt_str;
        const float* bias = biasB + (size_t)e*bias_str + 65280;
        const float* M = MB + (size_t)e*m_str;
        const f16* Dc = p.DP + (size_t)e*DP_E + (size_t)par*DP_B;
        f16* Dn = p.DP + (size_t)e*DP_E + (size_t)(par^1)*DP_B;
        f16* PTn = p.PT + (size_t)e*PT_E + (size_t)(par^1)*PT_B;
        float* ZR = p.ZR + (size_t)e*NB*64;
        float* Hs = HstB + (size_t)e*NB*64;
        int o0 = ob*64, r0 = rt*64;
        const f16* ap[2]; const f16* bp[2];
        #pragma unroll
        for (int a = 0; a < 2; a++) ap[a] = Wt + (size_t)(o0 + wm*32 + a*16 + l15)*352;
        #pragma unroll
        for (int bt = 0; bt < 2; bt++) bp[bt] = Dc + (size_t)(r0 + wn*32 + bt*16 + l15)*352;
        f32x4 acc[2][2] = {};
        #pragma unroll
        for (int k0 = 0; k0 < 352; k0 += 32) {
            f16x8 af[2], bf[2];
            #pragma unroll
            for (int a = 0; a < 2; a++) af[a] = *(const f16x8*)(ap[a] + k0 + lk*8);
            #pragma unroll
            for (int bt = 0; bt < 2; bt++) bf[bt] = *(const f16x8*)(bp[bt] + k0 + lk*8);
            #pragma unroll
            for (int a = 0; a < 2; a++)
                #pragma unroll
                for (int bt = 0; bt < 2; bt++)
                    acc[a][bt] = __builtin_amdgcn_mfma_f32_16x16x32_f16(af[a], bf[bt], acc[a][bt], 0,0,0);
        }
        #pragma unroll
        for (int bt = 0; bt < 2; bt++) {
            int r = r0 + wn*32 + bt*16 + l15;
            if (r < NB) {
                int n = r >> 5, b = r & 31;
                float tvb = tvp[b];
                #pragma unroll
                for (int a = 0; a < 2; a++) {
                    int oo = o0 + wm*32 + a*16 + lk*4;
                    float4 bs = *(const float4*)(bias + oo);
                    float4 ms = *(const float4*)(M + (size_t)n*128 + oo);
                    float p0 = acc[a][bt][0] + bs.x + tvb*ms.x;
                    float p1 = acc[a][bt][1] + bs.y + tvb*ms.y;
                    float p2 = acc[a][bt][2] + bs.z + tvb*ms.z;
                    float p3 = acc[a][bt][3] + bs.w + tvb*ms.w;
                    float s0 = 1.0f/(1.0f+expf(-p0)), s1 = 1.0f/(1.0f+expf(-p1));
                    float s2 = 1.0f/(1.0f+expf(-p2)), s3 = 1.0f/(1.0f+expf(-p3));
                    if (oo < 64) {
                        *(float4*)(ZR + (size_t)r*64 + oo) = make_float4(s0,s1,s2,s3);
                    } else {
                        int oh = oo - 64;
                        float4 h4 = *(const float4*)(Hs + (size_t)r*64 + oh);
                        float g0 = s0*h4.x, g1 = s1*h4.y, g2 = s2*h4.z, g3 = s3*h4.w;
                        st4h(Dn + (size_t)r*352 + 4 + oh, g0, g1, g2, g3);
                        size_t pb = (size_t)(b*68 + 4 + oh)*352 + n;
                        PTn[pb]       = (f16)g0;
                        PTn[pb + 352] = (f16)g1;
                        PTn[pb + 704] = (f16)g2;
                        PTn[pb + 1056]= (f16)g3;
                    }
                }
            }
        }
        if (ob == 0) {
            int row = tid >> 2, q = tid & 3;
            int r = r0 + row;
            if (r < NB) {
                f16 v = Dc[(size_t)r*352 + q];
                Dn[(size_t)r*352 + q] = v;
                PTn[(size_t)((r & 31)*68 + q)*352 + (r >> 5)] = v;
            }
        }
    }
}

__device__ void phase_proj1_enc(const KParams& p, int par, int t) {
    int tid = threadIdx.x;
    int lane = tid & 63, w = tid >> 6;
    int wm = w >> 1, wn = w & 1;
    int l15 = lane & 15, lk = lane >> 4;
    int ntiles = 163*2;
    for (int idx = blockIdx.x; idx < ntiles; idx += gridDim.x) {
        int rt = idx % 163, e = idx / 163;
        const f16* Wt = p.Wt + (size_t)e*WT_SET + 128*352;
        const float* bias = p.Weff + (size_t)e*WSET + 65408;
        const float* M = p.Mw + (size_t)e*M_SET + 325*128;
        const f16* Dc = p.DP + (size_t)e*DP_E + (size_t)par*DP_B;
        f16* Dn = p.DP + (size_t)e*DP_E + (size_t)(par^1)*DP_B;
        f16* PTn = p.PT + (size_t)e*PT_E + (size_t)(par^1)*PT_B;
        float* ZR = p.ZR + (size_t)e*NB*64;
        float* Hs = p.Henc + (size_t)e*NB*64;
        const float* tvv = p.tv + (size_t)t*32;
        int r0 = rt*64;
        const f16* ap[2]; const f16* bp[2];
        #pragma unroll
        for (int a = 0; a < 2; a++) ap[a] = Wt + (size_t)(wm*32 + a*16 + l15)*352;
        #pragma unroll
        for (int bt = 0; bt < 2; bt++) bp[bt] = Dc + (size_t)(r0 + wn*32 + bt*16 + l15)*352;
        f32x4 acc[2][2] = {};
        #pragma unroll
        for (int k0 = 0; k0 < 352; k0 += 32) {
            f16x8 af[2], bf[2];
            #pragma unroll
            for (int a = 0; a < 2; a++) af[a] = *(const f16x8*)(ap[a] + k0 + lk*8);
            #pragma unroll
            for (int bt = 0; bt < 2; bt++) bf[bt] = *(const f16x8*)(bp[bt] + k0 + lk*8);
            #pragma unroll
            for (int a = 0; a < 2; a++)
                #pragma unroll
                for (int bt = 0; bt < 2; bt++)
                    acc[a][bt] = __builtin_amdgcn_mfma_f32_16x16x32_f16(af[a], bf[bt], acc[a][bt], 0,0,0);
        }
        #pragma unroll
        for (int bt = 0; bt < 2; bt++) {
            int r = r0 + wn*32 + bt*16 + l15;
            if (r < NB) {
                int n = r >> 5, b = r & 31;
                float tvb = tvv[b];
                #pragma unroll
                for (int a = 0; a < 2; a++) {
                    int oo = wm*32 + a*16 + lk*4;
                    float4 bs = *(const float4*)(bias + oo);
                    float4 ms = *(const float4*)(M + (size_t)n*64 + oo);
                    float p0 = acc[a][bt][0] + bs.x + tvb*ms.x;
                    float p1 = acc[a][bt][1] + bs.y + tvb*ms.y;
                    float p2 = acc[a][bt][2] + bs.z + tvb*ms.z;
                    float p3 = acc[a][bt][3] + bs.w + tvb*ms.w;
                    float4 z4 = *(const float4*)(ZR + (size_t)r*64 + oo);
                    float4 h4 = *(const float4*)(Hs + (size_t)r*64 + oo);
                    float h0 = z4.x*h4.x + (1.0f - z4.x)*tanhf(p0);
                    float h1 = z4.y*h4.y + (1.0f - z4.y)*tanhf(p1);
                    float h2 = z4.z*h4.z + (1.0f - z4.z)*tanhf(p2);
                    float h3 = z4.w*h4.w + (1.0f - z4.w)*tanhf(p3);
                    *(float4*)(Hs + (size_t)r*64 + oo) = make_float4(h0,h1,h2,h3);
                    st4h(Dn + (size_t)r*352 + 4 + oo, h0, h1, h2, h3);
                    size_t pb = (size_t)(b*68 + 4 + oo)*352 + n;
                    PTn[pb]       = (f16)h0;
                    PTn[pb + 352] = (f16)h1;
                    PTn[pb + 704] = (f16)h2;
                    PTn[pb + 1056]= (f16)h3;
                }
            }
        }
        const f16* xn = nullptr;
        if (t < TENC-1) xn = p.xs + (size_t)(e*TENC + t + 1)*NB*4;
        if (xn) {
            int row = tid >> 2, q = tid & 3;
            int r = r0 + row;
            if (r < NB) {
                f16 v = (q < 3) ? xn[(size_t)r*4 + q] : (f16)0.0f;
                Dn[(size_t)r*352 + q] = v;
                PTn[(size_t)((r & 31)*68 + q)*352 + (r >> 5)] = v;
            }
        }
    }
}

__device__ void phase_proj1_dec(const KParams& p, int par, int t, f16* smem) {
    int tid = threadIdx.x;
    int lane = tid & 63, w = tid >> 6;
    int wm = w >> 1, wn = w & 1;
    int l15 = lane & 15, lk = lane >> 4;
    const f16* Wt = p.Wt + 2*WT_SET + 128*352;
    const float* bias = p.Weff + 2*WSET + 65408;
    const float* M = p.Mw + 2*M_SET + 325*128;
    const f16* Dc = p.DP + (size_t)par*DP_B;
    f16* Dn = p.DP + (size_t)(par^1)*DP_B;
    f16* PTn = p.PT + (size_t)(par^1)*PT_B;
    const float* tvv = p.tv + (size_t)(6 + t)*32;
    for (int idx = blockIdx.x; idx < 163; idx += gridDim.x) {
        int r0 = idx*64;
        const f16* ap[2]; const f16* bp[2];
        #pragma unroll
        for (int a = 0; a < 2; a++) ap[a] = Wt + (size_t)(wm*32 + a*16 + l15)*352;
        #pragma unroll
        for (int bt = 0; bt < 2; bt++) bp[bt] = Dc + (size_t)(r0 + wn*32 + bt*16 + l15)*352;
        f32x4 acc[2][2] = {};
        #pragma unroll
        for (int k0 = 0; k0 < 352; k0 += 32) {
            f16x8 af[2], bf[2];
            #pragma unroll
            for (int a = 0; a < 2; a++) af[a] = *(const f16x8*)(ap[a] + k0 + lk*8);
            #pragma unroll
            for (int bt = 0; bt < 2; bt++) bf[bt] = *(const f16x8*)(bp[bt] + k0 + lk*8);
            #pragma unroll
            for (int a = 0; a < 2; a++)
                #pragma unroll
                for (int bt = 0; bt < 2; bt++)
                    acc[a][bt] = __builtin_amdgcn_mfma_f32_16x16x32_f16(af[a], bf[bt], acc[a][bt], 0,0,0);
        }
        #pragma unroll
        for (int bt = 0; bt < 2; bt++) {
            int r = r0 + wn*32 + bt*16 + l15;
            int rl = wn*32 + bt*16 + l15;
            if (r < NB) {
                int n = r >> 5, b = r & 31;
                float tvb = tvv[b];
                #pragma unroll
                for (int a = 0; a < 2; a++) {
                    int oo = wm*32 + a*16 + lk*4;
                    float4 bs = *(const float4*)(bias + oo);
                    float4 ms = *(const float4*)(M + (size_t)n*64 + oo);
                    float p0 = acc[a][bt][0] + bs.x + tvb*ms.x;
                    float p1 = acc[a][bt][1] + bs.y + tvb*ms.y;
                    float p2 = acc[a][bt][2] + bs.z + tvb*ms.z;
                    float p3 = acc[a][bt][3] + bs.w + tvb*ms.w;
                    float4 z4 = *(const float4*)(p.ZR + (size_t)r*64 + oo);
                    float4 h4 = *(const float4*)(p.Hdec + (size_t)r*64 + oo);
                    float h0 = z4.x*h4.x + (1.0f - z4.x)*tanhf(p0);
                    float h1 = z4.y*h4.y + (1.0f - z4.y)*tanhf(p1);
                    float h2 = z4.z*h4.z + (1.0f - z4.z)*tanhf(p2);
                    float h3 = z4.w*h4.w + (1.0f - z4.w)*tanhf(p3);
                    *(float4*)(p.Hdec + (size_t)r*64 + oo) = make_float4(h0,h1,h2,h3);
                    st4h(Dn + (size_t)r*352 + 4 + oo, h0, h1, h2, h3);
                    size_t pb = (size_t)(b*68 + 4 + oo)*352 + n;
                    PTn[pb]       = (f16)h0;
                    PTn[pb + 352] = (f16)h1;
                    PTn[pb + 704] = (f16)h2;
                    PTn[pb + 1056]= (f16)h3;
                    st4h(smem + rl*68 + oo, h0, h1, h2, h3);
                }
            }
        }
        __syncthreads();
        // fc from LDS H, write DIRECTLY to final out layout
        for (int q = tid; q < 192; q += 256) {
            int row = q / 3, c = q - row*3;
            int r = r0 + row;
            if (r < NB) {
                float a = p.bfc[c];
                #pragma unroll 8
                for (int k = 0; k < 64; k++)
                    a = fmaf((float)smem[row*68 + k], p.Wfc[k*3 + c], a);
                int n = r >> 5, b = r & 31;
                int qq = t*3 + c;
                int oq = qq / 12, lq = qq - oq*12;
                p.out[(((size_t)b*3 + oq)*NN + n)*12 + lq] = a;
                if (t < TDEC-1) {
                    Dn[(size_t)r*352 + c] = (f16)a;
                    PTn[(size_t)((r & 31)*68 + c)*352 + (r >> 5)] = (f16)a;
                }
            }
        }
        if (t < TDEC-1 && tid < 64) {
            int r = r0 + tid;
            if (r < NB) {
                Dn[(size_t)r*352 + 3] = (f16)0.0f;
                PTn[(size_t)((r & 31)*68 + 3)*352 + (r >> 5)] = (f16)0.0f;
            }
        }
        __syncthreads();
    }
}

__device__ void phase_fuse(const KParams& p, f16* smem) {
    int tid = threadIdx.x;
    int lane = tid & 63, wave = tid >> 6;
    int wm = wave >> 1, wn = wave & 1;
    int l15 = lane & 15, lk = lane >> 4;
    const float* H1 = p.Henc;
    const float* H2 = p.Henc + (size_t)NB*64;
    unsigned* La = (unsigned*)smem;
    f16* Dn = p.DP;
    f16* PTn = p.PT;
    for (int idx = blockIdx.x; idx < 163; idx += gridDim.x) {
        int r0 = idx*64;
        for (int l = tid; l < 64*64; l += 256) {
            int i = l >> 6, k = l & 63;
            int r = r0 + i;
            unsigned val = 0;
            if (r < NB) {
                int n = r >> 5;
                float h1 = H1[(size_t)r*64 + k], h2 = H2[(size_t)r*64 + k];
                float s = h1 + h2;
                val = pk2(s*p.wL[n*64+k] + 2.0f*p.bL[n*64+k],
                          s*p.wH[n*64+k] + 2.0f*p.bH[n*64+k]);
            }
            La[i*132 + k] = val;
        }
        for (int l = tid; l < 64*32; l += 256) {
            int i = l >> 5, kp = l & 31;
            int r = r0 + i;
            unsigned v1 = 0, v2 = 0;
            if (r < NB) {
                float2 a = *(const float2*)(H1 + (size_t)r*64 + 2*kp);
                float2 b = *(const float2*)(H2 + (size_t)r*64 + 2*kp);
                v1 = pk2(a.x, a.y);
                v2 = pk2(b.x, b.y);
            }
            La[i*132 + 64 + kp] = v1;
            La[i*132 + 96 + kp] = v2;
        }
        __syncthreads();
        f32x4 acc[2][2] = {};
        for (int k0 = 0; k0 < 256; k0 += 32) {
            f16x8 afr[2], bfr[2];
            #pragma unroll
            for (int a = 0; a < 2; a++)
                afr[a] = ld8_lds(smem + (wm*32 + a*16 + l15)*264 + k0 + lk*8);
            #pragma unroll
            for (int b = 0; b < 2; b++)
                bfr[b] = *(const f16x8*)(p.Wfuse + (size_t)(wn*32 + b*16 + l15)*256 + k0 + lk*8);
            #pragma unroll
            for (int a = 0; a < 2; a++)
                #pragma unroll
                for (int b = 0; b < 2; b++)
                    acc[a][b] = __builtin_amdgcn_mfma_f32_16x16x32_f16(afr[a], bfr[b], acc[a][b], 0,0,0);
        }
        #pragma unroll
        for (int a = 0; a < 2; a++) {
            #pragma unroll
            for (int b = 0; b < 2; b++) {
                int o = wn*32 + b*16 + l15;
                float bo = 0.3f*p.bcam[o] + 0.7f*p.bagg[o];
                #pragma unroll
                for (int rr = 0; rr < 4; rr++) {
                    int r = r0 + wm*32 + a*16 + lk*4 + rr;
                    if (r >= NB) continue;
                    float val = acc[a][b][rr] + bo;
                    p.Hdec[(size_t)r*64 + o] = val;
                    Dn[(size_t)r*352 + 4 + o] = (f16)val;
                    PTn[(size_t)((r & 31)*68 + 4 + o)*352 + (r >> 5)] = (f16)val;
                }
            }
        }
        {
            int r = r0 + (tid >> 2), q = tid & 3;
            if (r < NB) {
                Dn[(size_t)r*352 + q] = (f16)0.0f;
                PTn[(size_t)((r & 31)*68 + q)*352 + (r >> 5)] = (f16)0.0f;
            }
        }
        __syncthreads();
    }
}

// ---------------- wrappers (split launches) ----------------
__global__ __launch_bounds__(256) void g_diff(KParams p, int par, int E) { phase_diff(p, par, E); }
__global__ __launch_bounds__(256) void g_proj0e(KParams p, int par, int t) {
    phase_proj0(p, par, 2, p.Wt, WT_SET, p.Weff, WSET, p.Mw, M_SET,
                p.tv + (size_t)t*32, p.Henc);
}
__global__ __launch_bounds__(256) void g_proj0d(KParams p, int par, int t) {
    phase_proj0(p, par, 1, p.Wt + 2*WT_SET, 0, p.Weff + 2*WSET, 0,
                p.Mw + 2*M_SET, 0, p.tv + (size_t)(6 + t)*32, p.Hdec);
}
__global__ __launch_bounds__(256) void g_proj1e(KParams p, int par, int t) { phase_proj1_enc(p, par, t); }
__global__ __launch_bounds__(256) void g_proj1d(KParams p, int par, int t) {
    __shared__ f16 smem[64*68];
    phase_proj1_dec(p, par, t, smem);
}
__global__ __launch_bounds__(256) void g_fuse(KParams p) {
    __shared__ f16 smem[64*264];
    phase_fuse(p, smem);
}

// ---------------- host ----------------
extern "C" void kernel_launch(void* const* d_in, const int* in_sizes, int n_in,
                              void* d_out, int out_size, void* d_ws, size_t ws_size,
                              hipStream_t stream) {
    const float* x      = (const float*)d_in[0];
    const float* st     = (const float*)d_in[1];
    const float* adj    = (const float*)d_in[2];
    const float* P      = (const float*)d_in[3];
    const float* H1_0   = (const float*)d_in[4];
    const float* H2_0   = (const float*)d_in[6];
    const float* W_encD = (const float*)d_in[8];
    const float* b_encD = (const float*)d_in[9];
    const float* W_encAD= (const float*)d_in[10];
    const float* b_encAD= (const float*)d_in[11];
    const float* W_dec  = (const float*)d_in[12];
    const float* b_dec  = (const float*)d_in[13];
    const float* W_fc   = (const float*)d_in[14];
    const float* b_fc   = (const float*)d_in[15];
    const float* W_aggH = (const float*)d_in[16];
    const float* b_aggH = (const float*)d_in[17];
    const float* W_camH = (const float*)d_in[20];
    const float* b_camH = (const float*)d_in[21];
    const float* wL     = (const float*)d_in[24];
    const float* bL     = (const float*)d_in[25];
    const float* wH     = (const float*)d_in[26];
    const float* bH     = (const float*)d_in[27];

    float* ws   = (float*)d_ws;
    float* G    = ws + OFF_G;
    float* rs   = ws + OFF_RS;
    float* cs   = rs + NN;
    float* rv   = ws + OFF_RV;
    float* Weff = ws + OFF_WEFF;
    f16*   Wt   = (f16*)(ws + OFF_WT);
    f16*   G16  = (f16*)(ws + OFF_G16);
    float* Mw   = ws + OFF_M;
    f16*   Wf   = (f16*)(ws + OFF_WF);
    float* tv   = ws + OFF_TV;
    f16*   xs   = (f16*)(ws + OFF_XS);
    f16*   PT   = (f16*)(ws + OFF_PT);
    f16*   DP   = (f16*)(ws + OFF_DP);
    float* ZR   = ws + OFF_ZR;
    float* G2   = ZR;
    float* Henc = ws + OFF_HENC;
    float* Hdec = ws + OFF_HDEC;

    // ---- prep ----
    k_sums<<<NN, 64, 0, stream>>>(adj, rs, cs);
    k_buildG<<<(NN*NN + 255)/256, 256, 0, stream>>>(adj, P, rs, cs, G);
    k_gg<<<dim3(11,11,2), 256, 0, stream>>>(G, G2);
    k_g16<<<(4*G16_MAT + 255)/256, 256, 0, stream>>>(G, G2, G16);
    k_rowsum<<<650, 64, 0, stream>>>(G, G2, rv);
    k_weff3<<<dim3(255,3), 256, 0, stream>>>(W_encD, b_encD, W_encAD, b_encAD,
                                             W_dec, b_dec, Weff);
    k_wt3<<<dim3((192*352 + 255)/256, 3), 256, 0, stream>>>(Weff, Wt);
    k_M3<<<dim3((325*192 + 255)/256, 3), 256, 0, stream>>>(Weff, rv, Mw);
    k_wfuse<<<64, 256, 0, stream>>>(W_camH, W_aggH, Wf);
    k_tv<<<3, 256, 0, stream>>>(st, tv);
    k_xs16<<<(2*TENC*NB*4 + 255)/256, 256, 0, stream>>>(x, xs);
    k_initH<<<(2*NB*64 + 255)/256, 256, 0, stream>>>(H1_0, H2_0, Henc);
    k_initDP<<<(2*NB*92 + 255)/256, 256, 0, stream>>>(xs, H1_0, H2_0, DP);
    k_initPT<<<(2*2176*352 + 255)/256, 256, 0, stream>>>(xs, H1_0, H2_0, PT);

    KParams prm;
    prm.G16 = G16; prm.PT = PT; prm.DP = DP;
    prm.Wt = Wt; prm.Weff = Weff; prm.Mw = Mw; prm.tv = tv;
    prm.ZR = ZR; prm.Henc = Henc; prm.Hdec = Hdec;
    prm.xs = xs;
    prm.wL = wL; prm.bL = bL; prm.wH = wH; prm.bH = bH;
    prm.bcam = b_camH; prm.bagg = b_aggH; prm.Wfuse = Wf;
    prm.Wfc = W_fc; prm.bfc = b_fc;
    prm.out = (float*)d_out;

    int par = 0;
    for (int t = 0; t < TENC; t++) {
        g_diff<<<1428, 256, 0, stream>>>(prm, par, 2);
        g_proj0e<<<652, 256, 0, stream>>>(prm, par, t);
        par ^= 1;
        g_diff<<<1428, 256, 0, stream>>>(prm, par, 2);
        g_proj1e<<<326, 256, 0, stream>>>(prm, par, t);
        par ^= 1;
    }
    g_fuse<<<163, 256, 0, stream>>>(prm);
    for (int t = 0; t < TDEC; t++) {
        g_diff<<<714, 256, 0, stream>>>(prm, par, 1);
        g_proj0d<<<326, 256, 0, stream>>>(prm, par, t);
        par ^= 1;
        g_diff<<<714, 256, 0, stream>>>(prm, par, 1);
        g_proj1d<<<163, 256, 0, stream>>>(prm, par, t);
        par ^= 1;
    }
}

// Round 11
// 1190.070 us; speedup vs baseline: 5.3559x; 1.1410x over previous
//
#include <hip/hip_runtime.h>
#include <math.h>

#define NN 325
#define BB 32
#define NB (NN*BB)            // 10400
#define TENC 6
#define TDEC 12
#define WSET 65472            // fp32 Weff: Wzr(340x128)+Wc(340x64)+bzr(128)+bc(64)
#define WT_SET (192*352)      // f16 transposed weights per set
#define M_SET (325*192)       // Mzr[325][128] + Mc[325][64]
#define G16_MAT (384*352)
#define PT_B 765952ull        // 2176*352 f16 per buf
#define PT_E 1531904ull
#define DP_B 3660800ull       // 10400*352 f16 per buf
#define DP_E 7321600ull
#define NGB 176               // proj blocks: 11 n-groups x 16 b-pairs

typedef _Float16 f16;
typedef f16 f16x4 __attribute__((ext_vector_type(4)));
typedef f16 f16x8 __attribute__((ext_vector_type(8)));
typedef float f32x4 __attribute__((ext_vector_type(4)));

static constexpr float ALPHA = 0.05f;
static constexpr float BETA  = 0.95f;
static constexpr float GAMMA = 0.95f;
static constexpr float ISQ2  = 0.7071067811865476f;

// ---------------- workspace offsets (floats) ----------------
static constexpr size_t OFF_G    = 0;
static constexpr size_t OFF_RS   = OFF_G + 2ull*NN*NN;
static constexpr size_t OFF_RV   = OFF_RS + 650;
static constexpr size_t OFF_WEFF = OFF_RV + 1300;
static constexpr size_t OFF_WT   = OFF_WEFF + 3ull*WSET;
static constexpr size_t OFF_G16  = OFF_WT + (3ull*WT_SET)/2;
static constexpr size_t OFF_M    = OFF_G16 + (4ull*G16_MAT)/2;
static constexpr size_t OFF_WF   = OFF_M + 3ull*M_SET;          // 64*256 f16 -> 8192
static constexpr size_t OFF_TV   = OFF_WF + 8192;               // 576
static constexpr size_t OFF_XS   = OFF_TV + 576;
static constexpr size_t OFF_PT   = OFF_XS + (2ull*TENC*NB*4)/2;
static constexpr size_t OFF_DP   = OFF_PT + (2ull*PT_E)/2;
static constexpr size_t OFF_ZR   = OFF_DP + (2ull*DP_E)/2;      // 2*NB*64 fp32 (G2 alias)
static constexpr size_t OFF_HENC = OFF_ZR + 2ull*NB*64;
static constexpr size_t OFF_HDEC = OFF_HENC + 2ull*NB*64;

__device__ inline unsigned pk2(float a, float b) {
    union { f16 h[2]; unsigned u; } x;
    x.h[0] = (f16)a; x.h[1] = (f16)b; return x.u;
}
__device__ inline void st4h(f16* p, float a, float b, float c, float d) {
    f16x4 v; v[0]=(f16)a; v[1]=(f16)b; v[2]=(f16)c; v[3]=(f16)d;
    *(f16x4*)p = v;
}
__device__ inline f16x8 ld8_lds(const f16* p) {
    f16x4 lo = *(const f16x4*)p;
    f16x4 hi = *(const f16x4*)(p + 4);
    f16x8 r;
    r[0]=lo[0]; r[1]=lo[1]; r[2]=lo[2]; r[3]=lo[3];
    r[4]=hi[0]; r[5]=hi[1]; r[6]=hi[2]; r[7]=hi[3];
    return r;
}

// ---------------- prep ----------------
__global__ void k_sums(const float* __restrict__ adj, float* rs, float* cs) {
    int v = blockIdx.x; int t = threadIdx.x;
    float sr = 0.f, sc = 0.f;
    for (int w = t; w < NN; w += 64) { sr += adj[v*NN + w]; sc += adj[w*NN + v]; }
    for (int o = 32; o > 0; o >>= 1) { sr += __shfl_down(sr, o); sc += __shfl_down(sc, o); }
    if (t == 0) { rs[v] = sr + 1.0f; cs[v] = sc + 1.0f; }
}

__global__ void k_buildG(const float* __restrict__ adj, const float* __restrict__ P,
                         const float* __restrict__ rs, const float* __restrict__ cs,
                         float* __restrict__ G) {
    int idx = blockIdx.x*256 + threadIdx.x;
    if (idx >= NN*NN) return;
    int w = idx / NN, v = idx % NN;
    float d = (v == w) ? 1.0f : 0.0f;
    float a1  = (adj[v*NN + w] + d) / rs[v];
    float a1t = (adj[w*NN + v] + d) / cs[v];
    float p = P[v*NN + w];
    G[idx]         = BETA*a1  + GAMMA*p;
    G[NN*NN + idx] = BETA*a1t + GAMMA*p;
}

__global__ __launch_bounds__(256) void k_gg(const float* __restrict__ G, float* __restrict__ G2) {
    int g = blockIdx.z;
    const float* A = G + (size_t)g*NN*NN;
    float* C = G2 + (size_t)g*NN*NN;
    int n0 = blockIdx.y*32, j0 = blockIdx.x*32;
    int tx = threadIdx.x & 31, ty = threadIdx.x >> 5;
    __shared__ float As[32][33];
    __shared__ float Bs[32][33];
    float acc[4] = {};
    for (int k0 = 0; k0 < NN; k0 += 32) {
        for (int l = threadIdx.x; l < 32*32; l += 256) {
            int i = l >> 5, kk = l & 31;
            int n = n0 + i, k = k0 + kk;
            As[i][kk] = (n < NN && k < NN) ? A[(size_t)n*NN + k] : 0.0f;
            int j = j0 + kk;
            Bs[i][kk] = (k0 + i < NN && j < NN) ? A[(size_t)(k0+i)*NN + j] : 0.0f;
        }
        __syncthreads();
        #pragma unroll 8
        for (int kk = 0; kk < 32; kk++) {
            float bv = Bs[kk][tx];
            #pragma unroll
            for (int i = 0; i < 4; i++) acc[i] = fmaf(As[ty + 8*i][kk], bv, acc[i]);
        }
        __syncthreads();
    }
    #pragma unroll
    for (int i = 0; i < 4; i++) {
        int n = n0 + ty + 8*i, j = j0 + tx;
        if (n < NN && j < NN) C[(size_t)n*NN + j] = acc[i];
    }
}

__global__ void k_g16(const float* __restrict__ G, const float* __restrict__ G2,
                      f16* __restrict__ G16) {
    int idx = blockIdx.x*256 + threadIdx.x;
    if (idx >= 4*G16_MAT) return;
    int m = idx / G16_MAT;
    int rem = idx - m*G16_MAT;
    int n = rem / 352, v = rem - n*352;
    int g = m >> 1, s = m & 1;
    float val = 0.0f;
    if (n < NN && v < NN) {
        float gv = G[(size_t)g*NN*NN + n*NN + v];
        float d = (n == v) ? ALPHA : 0.0f;
        val = (s == 0) ? (gv + d)
                       : (G2[(size_t)g*NN*NN + n*NN + v] + ALPHA*gv + d);
    }
    G16[idx] = (f16)val;
}

__global__ void k_rowsum(const float* __restrict__ G, const float* __restrict__ G2,
                         float* __restrict__ rv) {
    int row = blockIdx.x;
    int g = row / NN, n = row - g*NN;
    int t = threadIdx.x;
    float s1 = 0.f, s2 = 0.f;
    for (int v = t; v < NN; v += 64) {
        s1 += G[(size_t)g*NN*NN + n*NN + v];
        s2 += G2[(size_t)g*NN*NN + n*NN + v];
    }
    for (int o = 32; o > 0; o >>= 1) { s1 += __shfl_down(s1, o); s2 += __shfl_down(s2, o); }
    if (t == 0) {
        rv[(g*2 + 0)*NN + n] = ALPHA + s1;
        rv[(g*2 + 1)*NN + n] = ALPHA + ALPHA*s1 + s2;
    }
}

__global__ void k_weff3(const float* __restrict__ W0, const float* __restrict__ b0,
                        const float* __restrict__ W1, const float* __restrict__ b1,
                        const float* __restrict__ W2, const float* __restrict__ b2,
                        float* __restrict__ WeffAll) {
    int s = blockIdx.y;
    const float* W = (s == 0) ? W0 : (s == 1) ? W1 : W2;
    const float* b = (s == 0) ? b0 : (s == 1) ? b1 : b2;
    float* Wset = WeffAll + (size_t)s*WSET;
    float* Wzr = Wset;
    float* Wc  = Wset + 43520;
    float* bzr = Wset + 65280;
    float* bc  = Wset + 65408;
    int tid = blockIdx.x*256 + threadIdx.x;
    if (tid < 340*192) {
        int k = tid / 192, col = tid % 192;
        int g = col >> 6, oo = col & 63;
        const float* Wa = W + (2*g)*204*64;
        const float* Wb = W + (2*g+1)*204*64;
        float val;
        if (k < 68)       val = Wa[k*64+oo] + Wb[k*64+oo];
        else if (k < 204) val = Wa[k*64+oo];
        else              val = Wb[(k-136)*64+oo];
        if (g < 2) Wzr[k*128 + g*64 + oo] = val;
        else       Wc[k*64 + oo] = val;
    }
    if (blockIdx.x == 0 && threadIdx.x < 192) {
        int col = threadIdx.x, g = col >> 6, oo = col & 63;
        float bv = b[(2*g)*64+oo] + b[(2*g+1)*64+oo];
        if (g < 2) bzr[col] = bv; else bc[oo] = bv;
    }
}

__global__ void k_wt3(const float* __restrict__ WeffAll, f16* __restrict__ WtAll) {
    int s = blockIdx.y;
    const float* Weff = WeffAll + (size_t)s*WSET;
    f16* Wt = WtAll + (size_t)s*WT_SET;
    int idx = blockIdx.x*256 + threadIdx.x;
    if (idx >= 192*352) return;
    int o = idx / 352, k = idx - o*352;
    float v = 0.0f;
    if (k < 340) {
        int p = k / 68, c = k - p*68;
        if (c != 3) v = (o < 128) ? Weff[k*128 + o] : Weff[43520 + k*64 + (o - 128)];
    }
    Wt[idx] = (f16)v;
}

__global__ void k_M3(const float* __restrict__ WeffAll, const float* __restrict__ rv,
                     float* __restrict__ MAll) {
    int s = blockIdx.y;
    const float* Weff = WeffAll + (size_t)s*WSET;
    float* M = MAll + (size_t)s*M_SET;
    int idx = blockIdx.x*256 + threadIdx.x;
    if (idx >= 325*192) return;
    int n = idx / 192, q = idx - n*192;
    float acc;
    if (q < 128) {
        int o = q;
        acc = Weff[3*128 + o];
        #pragma unroll
        for (int p = 1; p <= 4; p++)
            acc += rv[(p-1)*NN + n] * Weff[(p*68 + 3)*128 + o];
        M[(size_t)n*128 + o] = acc;
    } else {
        int o = q - 128;
        acc = Weff[43520 + 3*64 + o];
        #pragma unroll
        for (int p = 1; p <= 4; p++)
            acc += rv[(p-1)*NN + n] * Weff[43520 + (p*68 + 3)*64 + o];
        M[325*128 + (size_t)n*64 + o] = acc;
    }
}

__global__ void k_wfuse(const float* __restrict__ Wcam, const float* __restrict__ Wagg,
                        f16* __restrict__ Wf) {
    int idx = blockIdx.x*256 + threadIdx.x;
    if (idx >= 64*256) return;
    int o = idx >> 8, k = idx & 255;
    float v = (k < 128) ? 0.3f*Wcam[(size_t)k*64 + o]
                        : 0.7f*Wagg[(size_t)(k-128)*64 + o];
    Wf[(size_t)o*256 + k] = (f16)v;
}

__global__ void k_tv(const float* __restrict__ st, float* __restrict__ tv) {
    int idx = blockIdx.x*256 + threadIdx.x;
    if (idx >= 18*32) return;
    int b = idx & 31, t = idx >> 5;
    float v;
    if (t < 6) {
        float hour   = (st[b*48 + 24 + 2*t] + 0.5f) * 23.0f;
        float minute = (st[b*48 + 36 + 2*t] + 0.5f) * 59.0f;
        v = floorf((hour*60.0f + minute) / 5.0f);
    } else {
        int td = t - 6;
        v = floorf((st[b*48 + 24 + td] + 0.5f) * 6.0f);
    }
    tv[idx] = v;
}

__global__ void k_xs16(const float* __restrict__ x, f16* __restrict__ xs) {
    int idx = blockIdx.x*256 + threadIdx.x;
    if (idx >= 2*TENC*NB*4) return;
    int c = idx & 3;
    int r = (idx >> 2) % NB;
    int t = (idx / (4*NB)) % TENC;
    int e = idx / (4*NB*TENC);
    int n = r / BB, b = r % BB;
    float val = 0.0f;
    if (c < 3) {
        float xe = x[((b*3 + c)*NN + n)*12 + 2*t];
        float xo = x[((b*3 + c)*NN + n)*12 + 2*t + 1];
        val = (e == 0) ? (xe - xo)*ISQ2 : (xe + xo)*ISQ2;
    }
    xs[idx] = (f16)val;
}

__global__ void k_initH(const float* __restrict__ H1_0, const float* __restrict__ H2_0,
                        float* __restrict__ Henc) {
    int idx = blockIdx.x*256 + threadIdx.x;
    if (idx >= 2*NB*64) return;
    int k = idx & 63;
    int r = (idx >> 6) % NB;
    int e = idx / (NB*64);
    int n = r / BB, b = r % BB;
    const float* src = e ? H2_0 : H1_0;
    Henc[idx] = src[((size_t)b*NN + n)*64 + k];
}

__global__ void k_initDP(const f16* __restrict__ xs, const float* __restrict__ H1_0,
                         const float* __restrict__ H2_0, f16* __restrict__ DP) {
    int idx = blockIdx.x*256 + threadIdx.x;
    if (idx >= 2*NB*92) return;
    int cc = idx % 92;
    int r = (idx / 92) % NB;
    int e = idx / (92*NB);
    int n = r >> 5, b = r & 31;
    f16* D0 = DP + (size_t)e*DP_E;
    if (cc < 68) {
        f16 v;
        if (cc < 3)       v = xs[(size_t)e*TENC*NB*4 + (size_t)r*4 + cc];
        else if (cc == 3) v = (f16)0.0f;
        else {
            const float* h0 = e ? H2_0 : H1_0;
            v = (f16)h0[((size_t)b*NN + n)*64 + (cc-4)];
        }
        D0[(size_t)r*352 + cc] = v;
    } else if (cc < 80) {
        D0[(size_t)r*352 + 340 + (cc-68)] = (f16)0.0f;
    } else {
        D0[DP_B + (size_t)r*352 + 340 + (cc-80)] = (f16)0.0f;
    }
}

__global__ void k_initPT(const f16* __restrict__ xs, const float* __restrict__ H1_0,
                         const float* __restrict__ H2_0, f16* __restrict__ PTb) {
    int idx = blockIdx.x*256 + threadIdx.x;
    if (idx >= 2*2176*352) return;
    int v = idx % 352;
    int j = (idx / 352) % 2176;
    int e = idx / (352*2176);
    f16* P0 = PTb + (size_t)e*PT_E;
    if (v >= NN) {
        P0[(size_t)j*352 + v] = (f16)0.0f;
        P0[PT_B + (size_t)j*352 + v] = (f16)0.0f;
        return;
    }
    int b = j / 68, c = j - b*68;
    f16 val;
    if (c < 3)       val = xs[(size_t)e*TENC*NB*4 + (size_t)(v*32+b)*4 + c];
    else if (c == 3) val = (f16)0.0f;
    else {
        const float* h0 = e ? H2_0 : H1_0;
        val = (f16)h0[((size_t)b*NN + v)*64 + (c-4)];
    }
    P0[(size_t)j*352 + v] = val;
}

// ================= phases =================
struct KParams {
    const f16* G16;
    f16* PT;
    f16* DP;
    const f16* Wt;
    const float* Weff;
    const float* Mw;
    const float* tv;
    float* ZR;
    float* Henc;
    float* Hdec;
    const f16* xs;
    const float* wL; const float* bL; const float* wH; const float* bH;
    const float* bcam; const float* bagg;
    const f16* Wfuse;
    const float* Wfc; const float* bfc;
    float* out;
};

__device__ void phase_diff(const KParams& p, int par, int E) {
    int tid = threadIdx.x;
    int lane = tid & 63, w = tid >> 6;
    int wm = w >> 1, wn = w & 1;
    int l15 = lane & 15, lk = lane >> 4;
    int ntiles = 34*21*E;
    for (int idx = blockIdx.x; idx < ntiles; idx += gridDim.x) {
        int jt = idx % 34, rem = idx / 34;
        int Rt = rem % 21, e = rem / 21;
        const f16* X = p.PT + (size_t)e*PT_E + (size_t)par*PT_B;
        f16* D = p.DP + (size_t)e*DP_E + (size_t)par*DP_B;
        int j0 = jt*64, R0 = Rt*64;
        const f16* ap[2];
        #pragma unroll
        for (int a = 0; a < 2; a++)
            ap[a] = X + (size_t)(j0 + wm*32 + a*16 + l15)*352;
        const f16* bp[2]; int mv[2], nv[2];
        #pragma unroll
        for (int bt = 0; bt < 2; bt++) {
            int R = R0 + wn*32 + bt*16 + l15;
            int ok = (R < 1300);
            int Rc = ok ? R : 0;
            int m = Rc / 325, n = Rc - m*325;
            mv[bt] = ok ? m : -1; nv[bt] = n;
            bp[bt] = p.G16 + (size_t)m*G16_MAT + (size_t)n*352;
        }
        f32x4 acc[2][2] = {};
        #pragma unroll
        for (int k0 = 0; k0 < 352; k0 += 32) {
            f16x8 af[2], bf[2];
            #pragma unroll
            for (int a = 0; a < 2; a++) af[a] = *(const f16x8*)(ap[a] + k0 + lk*8);
            #pragma unroll
            for (int bt = 0; bt < 2; bt++) bf[bt] = *(const f16x8*)(bp[bt] + k0 + lk*8);
            #pragma unroll
            for (int a = 0; a < 2; a++)
                #pragma unroll
                for (int bt = 0; bt < 2; bt++)
                    acc[a][bt] = __builtin_amdgcn_mfma_f32_16x16x32_f16(af[a], bf[bt], acc[a][bt], 0,0,0);
        }
        #pragma unroll
        for (int bt = 0; bt < 2; bt++) {
            if (mv[bt] < 0) continue;
            int m = mv[bt], n = nv[bt];
            #pragma unroll
            for (int a = 0; a < 2; a++) {
                int jb = j0 + wm*32 + a*16 + lk*4;
                int b = jb / 68, c = jb - b*68;
                f16* dst = D + (size_t)(n*32 + b)*352 + (m+1)*68 + c;
                st4h(dst, acc[a][bt][0], acc[a][bt][1], acc[a][bt][2], acc[a][bt][3]);
            }
        }
    }
}

// proj0: rows remapped so lane l15 spans consecutive n (coalesced PTn writes).
// block rt: ng = rt>>4 (n-group of 32), bp = rt&15 (b-pair); wave wn = b in pair.
__device__ void phase_proj0(const KParams& p, int par, int E,
        const f16* WtB, int wt_str, const float* biasB, int bias_str,
        const float* MB, int m_str, const float* tvp, float* HstB) {
    int tid = threadIdx.x;
    int lane = tid & 63, w = tid >> 6;
    int wm = w >> 1, wn = w & 1;
    int l15 = lane & 15, lk = lane >> 4;
    int ntiles = 2*NGB*E;
    for (int idx = blockIdx.x; idx < ntiles; idx += gridDim.x) {
        int ob = idx & 1, rem = idx >> 1;
        int rt = rem % NGB, e = rem / NGB;
        int ng = rt >> 4, bpx = rt & 15;
        const f16* Wt = WtB + (size_t)e*wt_str;
        const float* bias = biasB + (size_t)e*bias_str + 65280;
        const float* M = MB + (size_t)e*m_str;
        const f16* Dc = p.DP + (size_t)e*DP_E + (size_t)par*DP_B;
        f16* Dn = p.DP + (size_t)e*DP_E + (size_t)(par^1)*DP_B;
        f16* PTn = p.PT + (size_t)e*PT_E + (size_t)(par^1)*PT_B;
        float* ZR = p.ZR + (size_t)e*NB*64;
        float* Hs = HstB + (size_t)e*NB*64;
        int o0 = ob*64;
        int bcol = bpx*2 + wn;
        const f16* ap[2]; const f16* bfp[2];
        #pragma unroll
        for (int a = 0; a < 2; a++) ap[a] = Wt + (size_t)(o0 + wm*32 + a*16 + l15)*352;
        #pragma unroll
        for (int bt = 0; bt < 2; bt++) {
            int n = ng*32 + bt*16 + l15;
            int r = n*32 + bcol;
            int rc = (n < NN) ? r : 0;
            bfp[bt] = Dc + (size_t)rc*352;
        }
        f32x4 acc[2][2] = {};
        #pragma unroll
        for (int k0 = 0; k0 < 352; k0 += 32) {
            f16x8 af[2], bf[2];
            #pragma unroll
            for (int a = 0; a < 2; a++) af[a] = *(const f16x8*)(ap[a] + k0 + lk*8);
            #pragma unroll
            for (int bt = 0; bt < 2; bt++) bf[bt] = *(const f16x8*)(bfp[bt] + k0 + lk*8);
            #pragma unroll
            for (int a = 0; a < 2; a++)
                #pragma unroll
                for (int bt = 0; bt < 2; bt++)
                    acc[a][bt] = __builtin_amdgcn_mfma_f32_16x16x32_f16(af[a], bf[bt], acc[a][bt], 0,0,0);
        }
        #pragma unroll
        for (int bt = 0; bt < 2; bt++) {
            int n = ng*32 + bt*16 + l15;
            if (n < NN) {
                int b = bcol;
                int r = n*32 + b;
                float tvb = tvp[b];
                #pragma unroll
                for (int a = 0; a < 2; a++) {
                    int oo = o0 + wm*32 + a*16 + lk*4;
                    float4 bs = *(const float4*)(bias + oo);
                    float4 ms = *(const float4*)(M + (size_t)n*128 + oo);
                    float p0 = acc[a][bt][0] + bs.x + tvb*ms.x;
                    float p1 = acc[a][bt][1] + bs.y + tvb*ms.y;
                    float p2 = acc[a][bt][2] + bs.z + tvb*ms.z;
                    float p3 = acc[a][bt][3] + bs.w + tvb*ms.w;
                    float s0 = 1.0f/(1.0f+expf(-p0)), s1 = 1.0f/(1.0f+expf(-p1));
                    float s2 = 1.0f/(1.0f+expf(-p2)), s3 = 1.0f/(1.0f+expf(-p3));
                    if (oo < 64) {
                        *(float4*)(ZR + (size_t)r*64 + oo) = make_float4(s0,s1,s2,s3);
                    } else {
                        int oh = oo - 64;
                        float4 h4 = *(const float4*)(Hs + (size_t)r*64 + oh);
                        float g0 = s0*h4.x, g1 = s1*h4.y, g2 = s2*h4.z, g3 = s3*h4.w;
                        st4h(Dn + (size_t)r*352 + 4 + oh, g0, g1, g2, g3);
                        size_t pb = (size_t)(b*68 + 4 + oh)*352 + n;
                        PTn[pb]       = (f16)g0;
                        PTn[pb + 352] = (f16)g1;
                        PTn[pb + 704] = (f16)g2;
                        PTn[pb + 1056]= (f16)g3;
                    }
                }
            }
        }
        if (ob == 0) {
            int n_l = tid & 31, b_l = (tid >> 5) & 1, q = tid >> 6;
            int n = ng*32 + n_l;
            if (n < NN) {
                int b = bpx*2 + b_l;
                int r = n*32 + b;
                f16 v = Dc[(size_t)r*352 + q];
                Dn[(size_t)r*352 + q] = v;
                PTn[(size_t)(b*68 + q)*352 + n] = v;
            }
        }
    }
}

__device__ void phase_proj1_enc(const KParams& p, int par, int t) {
    int tid = threadIdx.x;
    int lane = tid & 63, w = tid >> 6;
    int wm = w >> 1, wn = w & 1;
    int l15 = lane & 15, lk = lane >> 4;
    int ntiles = NGB*2;
    for (int idx = blockIdx.x; idx < ntiles; idx += gridDim.x) {
        int rt = idx % NGB, e = idx / NGB;
        int ng = rt >> 4, bpx = rt & 15;
        const f16* Wt = p.Wt + (size_t)e*WT_SET + 128*352;
        const float* bias = p.Weff + (size_t)e*WSET + 65408;
        const float* M = p.Mw + (size_t)e*M_SET + 325*128;
        const f16* Dc = p.DP + (size_t)e*DP_E + (size_t)par*DP_B;
        f16* Dn = p.DP + (size_t)e*DP_E + (size_t)(par^1)*DP_B;
        f16* PTn = p.PT + (size_t)e*PT_E + (size_t)(par^1)*PT_B;
        float* ZR = p.ZR + (size_t)e*NB*64;
        float* Hs = p.Henc + (size_t)e*NB*64;
        const float* tvv = p.tv + (size_t)t*32;
        int bcol = bpx*2 + wn;
        const f16* ap[2]; const f16* bfp[2];
        #pragma unroll
        for (int a = 0; a < 2; a++) ap[a] = Wt + (size_t)(wm*32 + a*16 + l15)*352;
        #pragma unroll
        for (int bt = 0; bt < 2; bt++) {
            int n = ng*32 + bt*16 + l15;
            int r = n*32 + bcol;
            int rc = (n < NN) ? r : 0;
            bfp[bt] = Dc + (size_t)rc*352;
        }
        f32x4 acc[2][2] = {};
        #pragma unroll
        for (int k0 = 0; k0 < 352; k0 += 32) {
            f16x8 af[2], bf[2];
            #pragma unroll
            for (int a = 0; a < 2; a++) af[a] = *(const f16x8*)(ap[a] + k0 + lk*8);
            #pragma unroll
            for (int bt = 0; bt < 2; bt++) bf[bt] = *(const f16x8*)(bfp[bt] + k0 + lk*8);
            #pragma unroll
            for (int a = 0; a < 2; a++)
                #pragma unroll
                for (int bt = 0; bt < 2; bt++)
                    acc[a][bt] = __builtin_amdgcn_mfma_f32_16x16x32_f16(af[a], bf[bt], acc[a][bt], 0,0,0);
        }
        #pragma unroll
        for (int bt = 0; bt < 2; bt++) {
            int n = ng*32 + bt*16 + l15;
            if (n < NN) {
                int b = bcol;
                int r = n*32 + b;
                float tvb = tvv[b];
                #pragma unroll
                for (int a = 0; a < 2; a++) {
                    int oo = wm*32 + a*16 + lk*4;
                    float4 bs = *(const float4*)(bias + oo);
                    float4 ms = *(const float4*)(M + (size_t)n*64 + oo);
                    float p0 = acc[a][bt][0] + bs.x + tvb*ms.x;
                    float p1 = acc[a][bt][1] + bs.y + tvb*ms.y;
                    float p2 = acc[a][bt][2] + bs.z + tvb*ms.z;
                    float p3 = acc[a][bt][3] + bs.w + tvb*ms.w;
                    float4 z4 = *(const float4*)(ZR + (size_t)r*64 + oo);
                    float4 h4 = *(const float4*)(Hs + (size_t)r*64 + oo);
                    float h0 = z4.x*h4.x + (1.0f - z4.x)*tanhf(p0);
                    float h1 = z4.y*h4.y + (1.0f - z4.y)*tanhf(p1);
                    float h2 = z4.z*h4.z + (1.0f - z4.z)*tanhf(p2);
                    float h3 = z4.w*h4.w + (1.0f - z4.w)*tanhf(p3);
                    *(float4*)(Hs + (size_t)r*64 + oo) = make_float4(h0,h1,h2,h3);
                    st4h(Dn + (size_t)r*352 + 4 + oo, h0, h1, h2, h3);
                    size_t pb = (size_t)(b*68 + 4 + oo)*352 + n;
                    PTn[pb]       = (f16)h0;
                    PTn[pb + 352] = (f16)h1;
                    PTn[pb + 704] = (f16)h2;
                    PTn[pb + 1056]= (f16)h3;
                }
            }
        }
        const f16* xn = nullptr;
        if (t < TENC-1) xn = p.xs + (size_t)(e*TENC + t + 1)*NB*4;
        if (xn) {
            int n_l = tid & 31, b_l = (tid >> 5) & 1, q = tid >> 6;
            int n = ng*32 + n_l;
            if (n < NN) {
                int b = bpx*2 + b_l;
                int r = n*32 + b;
                f16 v = (q < 3) ? xn[(size_t)r*4 + q] : (f16)0.0f;
                Dn[(size_t)r*352 + q] = v;
                PTn[(size_t)(b*68 + q)*352 + n] = v;
            }
        }
    }
}

__device__ void phase_proj1_dec(const KParams& p, int par, int t, f16* smem) {
    int tid = threadIdx.x;
    int lane = tid & 63, w = tid >> 6;
    int wm = w >> 1, wn = w & 1;
    int l15 = lane & 15, lk = lane >> 4;
    const f16* Wt = p.Wt + 2*WT_SET + 128*352;
    const float* bias = p.Weff + 2*WSET + 65408;
    const float* M = p.Mw + 2*M_SET + 325*128;
    const f16* Dc = p.DP + (size_t)par*DP_B;
    f16* Dn = p.DP + (size_t)(par^1)*DP_B;
    f16* PTn = p.PT + (size_t)(par^1)*PT_B;
    const float* tvv = p.tv + (size_t)(6 + t)*32;
    for (int idx = blockIdx.x; idx < NGB; idx += gridDim.x) {
        int ng = idx >> 4, bpx = idx & 15;
        int bcol = bpx*2 + wn;
        const f16* ap[2]; const f16* bfp[2];
        #pragma unroll
        for (int a = 0; a < 2; a++) ap[a] = Wt + (size_t)(wm*32 + a*16 + l15)*352;
        #pragma unroll
        for (int bt = 0; bt < 2; bt++) {
            int n = ng*32 + bt*16 + l15;
            int r = n*32 + bcol;
            int rc = (n < NN) ? r : 0;
            bfp[bt] = Dc + (size_t)rc*352;
        }
        f32x4 acc[2][2] = {};
        #pragma unroll
        for (int k0 = 0; k0 < 352; k0 += 32) {
            f16x8 af[2], bf[2];
            #pragma unroll
            for (int a = 0; a < 2; a++) af[a] = *(const f16x8*)(ap[a] + k0 + lk*8);
            #pragma unroll
            for (int bt = 0; bt < 2; bt++) bf[bt] = *(const f16x8*)(bfp[bt] + k0 + lk*8);
            #pragma unroll
            for (int a = 0; a < 2; a++)
                #pragma unroll
                for (int bt = 0; bt < 2; bt++)
                    acc[a][bt] = __builtin_amdgcn_mfma_f32_16x16x32_f16(af[a], bf[bt], acc[a][bt], 0,0,0);
        }
        #pragma unroll
        for (int bt = 0; bt < 2; bt++) {
            int n = ng*32 + bt*16 + l15;
            int sl = wn*32 + bt*16 + l15;
            if (n < NN) {
                int b = bcol;
                int r = n*32 + b;
                float tvb = tvv[b];
                #pragma unroll
                for (int a = 0; a < 2; a++) {
                    int oo = wm*32 + a*16 + lk*4;
                    float4 bs = *(const float4*)(bias + oo);
                    float4 ms = *(const float4*)(M + (size_t)n*64 + oo);
                    float p0 = acc[a][bt][0] + bs.x + tvb*ms.x;
                    float p1 = acc[a][bt][1] + bs.y + tvb*ms.y;
                    float p2 = acc[a][bt][2] + bs.z + tvb*ms.z;
                    float p3 = acc[a][bt][3] + bs.w + tvb*ms.w;
                    float4 z4 = *(const float4*)(p.ZR + (size_t)r*64 + oo);
                    float4 h4 = *(const float4*)(p.Hdec + (size_t)r*64 + oo);
                    float h0 = z4.x*h4.x + (1.0f - z4.x)*tanhf(p0);
                    float h1 = z4.y*h4.y + (1.0f - z4.y)*tanhf(p1);
                    float h2 = z4.z*h4.z + (1.0f - z4.z)*tanhf(p2);
                    float h3 = z4.w*h4.w + (1.0f - z4.w)*tanhf(p3);
                    *(float4*)(p.Hdec + (size_t)r*64 + oo) = make_float4(h0,h1,h2,h3);
                    st4h(Dn + (size_t)r*352 + 4 + oo, h0, h1, h2, h3);
                    size_t pb = (size_t)(b*68 + 4 + oo)*352 + n;
                    PTn[pb]       = (f16)h0;
                    PTn[pb + 352] = (f16)h1;
                    PTn[pb + 704] = (f16)h2;
                    PTn[pb + 1056]= (f16)h3;
                    st4h(smem + sl*68 + oo, h0, h1, h2, h3);
                }
            }
        }
        __syncthreads();
        // fc from LDS H; write directly to final out layout
        for (int q = tid; q < 192; q += 256) {
            int slot = q & 63, c = q >> 6;
            int n = ng*32 + (slot & 31);
            if (n < NN) {
                int b = bpx*2 + (slot >> 5);
                int r = n*32 + b;
                float a = p.bfc[c];
                #pragma unroll 8
                for (int k = 0; k < 64; k++)
                    a = fmaf((float)smem[slot*68 + k], p.Wfc[k*3 + c], a);
                int qq = t*3 + c;
                int oq = qq / 12, lq = qq - oq*12;
                p.out[(((size_t)b*3 + oq)*NN + n)*12 + lq] = a;
                if (t < TDEC-1) {
                    Dn[(size_t)r*352 + c] = (f16)a;
                    PTn[(size_t)((size_t)(b*68 + c))*352 + n] = (f16)a;
                }
            }
        }
        if (t < TDEC-1 && tid < 64) {
            int slot = tid;
            int n = ng*32 + (slot & 31);
            if (n < NN) {
                int b = bpx*2 + (slot >> 5);
                int r = n*32 + b;
                Dn[(size_t)r*352 + 3] = (f16)0.0f;
                PTn[(size_t)(b*68 + 3)*352 + n] = (f16)0.0f;
            }
        }
        __syncthreads();
    }
}

// fuse with swapped operands (A = Wfuse rows, B = H-tile rows) so output col = n.
__device__ void phase_fuse(const KParams& p, f16* smem) {
    int tid = threadIdx.x;
    int lane = tid & 63, wave = tid >> 6;
    int wm = wave >> 1, wn = wave & 1;
    int l15 = lane & 15, lk = lane >> 4;
    const float* H1 = p.Henc;
    const float* H2 = p.Henc + (size_t)NB*64;
    unsigned* La = (unsigned*)smem;
    f16* Dn = p.DP;
    f16* PTn = p.PT;
    for (int idx = blockIdx.x; idx < NGB; idx += gridDim.x) {
        int ng = idx >> 4, bpx = idx & 15;
        // stage rows: local slot i -> n = ng*32 + (i&31), b = bpx*2 + (i>>5)
        for (int l = tid; l < 64*64; l += 256) {
            int i = l >> 6, k = l & 63;
            int n = ng*32 + (i & 31);
            unsigned val = 0;
            if (n < NN) {
                int b = bpx*2 + (i >> 5);
                int r = n*32 + b;
                float h1 = H1[(size_t)r*64 + k], h2 = H2[(size_t)r*64 + k];
                float s = h1 + h2;
                val = pk2(s*p.wL[n*64+k] + 2.0f*p.bL[n*64+k],
                          s*p.wH[n*64+k] + 2.0f*p.bH[n*64+k]);
            }
            La[i*132 + k] = val;
        }
        for (int l = tid; l < 64*32; l += 256) {
            int i = l >> 5, kp = l & 31;
            int n = ng*32 + (i & 31);
            unsigned v1 = 0, v2 = 0;
            if (n < NN) {
                int b = bpx*2 + (i >> 5);
                int r = n*32 + b;
                float2 a = *(const float2*)(H1 + (size_t)r*64 + 2*kp);
                float2 b2 = *(const float2*)(H2 + (size_t)r*64 + 2*kp);
                v1 = pk2(a.x, a.y);
                v2 = pk2(b2.x, b2.y);
            }
            La[i*132 + 64 + kp] = v1;
            La[i*132 + 96 + kp] = v2;
        }
        __syncthreads();
        // A = Wfuse rows (o), B = LDS rows (i): acc rows = o, cols(l15) = i
        f32x4 acc[2][2] = {};
        for (int k0 = 0; k0 < 256; k0 += 32) {
            f16x8 afr[2], bfr[2];
            #pragma unroll
            for (int a = 0; a < 2; a++)
                afr[a] = *(const f16x8*)(p.Wfuse + (size_t)(wn*32 + a*16 + l15)*256 + k0 + lk*8);
            #pragma unroll
            for (int bt = 0; bt < 2; bt++)
                bfr[bt] = ld8_lds(smem + (wm*32 + bt*16 + l15)*264 + k0 + lk*8);
            #pragma unroll
            for (int a = 0; a < 2; a++)
                #pragma unroll
                for (int bt = 0; bt < 2; bt++)
                    acc[a][bt] = __builtin_amdgcn_mfma_f32_16x16x32_f16(afr[a], bfr[bt], acc[a][bt], 0,0,0);
        }
        __syncthreads();   // smem reused next tile iteration
        #pragma unroll
        for (int bt = 0; bt < 2; bt++) {
            int i = wm*32 + bt*16 + l15;
            int n = ng*32 + (i & 31);
            if (n < NN) {
                int b = bpx*2 + (i >> 5);
                int r = n*32 + b;
                #pragma unroll
                for (int a = 0; a < 2; a++) {
                    int ob = wn*32 + a*16 + lk*4;
                    float v0 = acc[a][bt][0] + 0.3f*p.bcam[ob]   + 0.7f*p.bagg[ob];
                    float v1 = acc[a][bt][1] + 0.3f*p.bcam[ob+1] + 0.7f*p.bagg[ob+1];
                    float v2 = acc[a][bt][2] + 0.3f*p.bcam[ob+2] + 0.7f*p.bagg[ob+2];
                    float v3 = acc[a][bt][3] + 0.3f*p.bcam[ob+3] + 0.7f*p.bagg[ob+3];
                    *(float4*)(p.Hdec + (size_t)r*64 + ob) = make_float4(v0,v1,v2,v3);
                    st4h(Dn + (size_t)r*352 + 4 + ob, v0, v1, v2, v3);
                    size_t pb = (size_t)(b*68 + 4 + ob)*352 + n;
                    PTn[pb]       = (f16)v0;
                    PTn[pb + 352] = (f16)v1;
                    PTn[pb + 704] = (f16)v2;
                    PTn[pb + 1056]= (f16)v3;
                }
            }
        }
        {
            int n_l = tid & 31, b_l = (tid >> 5) & 1, q = tid >> 6;
            int n = ng*32 + n_l;
            if (n < NN) {
                int b = bpx*2 + b_l;
                int r = n*32 + b;
                Dn[(size_t)r*352 + q] = (f16)0.0f;
                PTn[(size_t)(b*68 + q)*352 + n] = (f16)0.0f;
            }
        }
        __syncthreads();
    }
}

// ---------------- wrappers (split launches) ----------------
__global__ __launch_bounds__(256) void g_diff(KParams p, int par, int E) { phase_diff(p, par, E); }
__global__ __launch_bounds__(256) void g_proj0e(KParams p, int par, int t) {
    phase_proj0(p, par, 2, p.Wt, WT_SET, p.Weff, WSET, p.Mw, M_SET,
                p.tv + (size_t)t*32, p.Henc);
}
__global__ __launch_bounds__(256) void g_proj0d(KParams p, int par, int t) {
    phase_proj0(p, par, 1, p.Wt + 2*WT_SET, 0, p.Weff + 2*WSET, 0,
                p.Mw + 2*M_SET, 0, p.tv + (size_t)(6 + t)*32, p.Hdec);
}
__global__ __launch_bounds__(256) void g_proj1e(KParams p, int par, int t) { phase_proj1_enc(p, par, t); }
__global__ __launch_bounds__(256) void g_proj1d(KParams p, int par, int t) {
    __shared__ f16 smem[64*68];
    phase_proj1_dec(p, par, t, smem);
}
__global__ __launch_bounds__(256) void g_fuse(KParams p) {
    __shared__ f16 smem[64*264];
    phase_fuse(p, smem);
}

// ---------------- host ----------------
extern "C" void kernel_launch(void* const* d_in, const int* in_sizes, int n_in,
                              void* d_out, int out_size, void* d_ws, size_t ws_size,
                              hipStream_t stream) {
    const float* x      = (const float*)d_in[0];
    const float* st     = (const float*)d_in[1];
    const float* adj    = (const float*)d_in[2];
    const float* P      = (const float*)d_in[3];
    const float* H1_0   = (const float*)d_in[4];
    const float* H2_0   = (const float*)d_in[6];
    const float* W_encD = (const float*)d_in[8];
    const float* b_encD = (const float*)d_in[9];
    const float* W_encAD= (const float*)d_in[10];
    const float* b_encAD= (const float*)d_in[11];
    const float* W_dec  = (const float*)d_in[12];
    const float* b_dec  = (const float*)d_in[13];
    const float* W_fc   = (const float*)d_in[14];
    const float* b_fc   = (const float*)d_in[15];
    const float* W_aggH = (const float*)d_in[16];
    const float* b_aggH = (const float*)d_in[17];
    const float* W_camH = (const float*)d_in[20];
    const float* b_camH = (const float*)d_in[21];
    const float* wL     = (const float*)d_in[24];
    const float* bL     = (const float*)d_in[25];
    const float* wH     = (const float*)d_in[26];
    const float* bH     = (const float*)d_in[27];

    float* ws   = (float*)d_ws;
    float* G    = ws + OFF_G;
    float* rs   = ws + OFF_RS;
    float* cs   = rs + NN;
    float* rv   = ws + OFF_RV;
    float* Weff = ws + OFF_WEFF;
    f16*   Wt   = (f16*)(ws + OFF_WT);
    f16*   G16  = (f16*)(ws + OFF_G16);
    float* Mw   = ws + OFF_M;
    f16*   Wf   = (f16*)(ws + OFF_WF);
    float* tv   = ws + OFF_TV;
    f16*   xs   = (f16*)(ws + OFF_XS);
    f16*   PT   = (f16*)(ws + OFF_PT);
    f16*   DP   = (f16*)(ws + OFF_DP);
    float* ZR   = ws + OFF_ZR;
    float* G2   = ZR;
    float* Henc = ws + OFF_HENC;
    float* Hdec = ws + OFF_HDEC;

    // ---- prep ----
    k_sums<<<NN, 64, 0, stream>>>(adj, rs, cs);
    k_buildG<<<(NN*NN + 255)/256, 256, 0, stream>>>(adj, P, rs, cs, G);
    k_gg<<<dim3(11,11,2), 256, 0, stream>>>(G, G2);
    k_g16<<<(4*G16_MAT + 255)/256, 256, 0, stream>>>(G, G2, G16);
    k_rowsum<<<650, 64, 0, stream>>>(G, G2, rv);
    k_weff3<<<dim3(255,3), 256, 0, stream>>>(W_encD, b_encD, W_encAD, b_encAD,
                                             W_dec, b_dec, Weff);
    k_wt3<<<dim3((192*352 + 255)/256, 3), 256, 0, stream>>>(Weff, Wt);
    k_M3<<<dim3((325*192 + 255)/256, 3), 256, 0, stream>>>(Weff, rv, Mw);
    k_wfuse<<<64, 256, 0, stream>>>(W_camH, W_aggH, Wf);
    k_tv<<<3, 256, 0, stream>>>(st, tv);
    k_xs16<<<(2*TENC*NB*4 + 255)/256, 256, 0, stream>>>(x, xs);
    k_initH<<<(2*NB*64 + 255)/256, 256, 0, stream>>>(H1_0, H2_0, Henc);
    k_initDP<<<(2*NB*92 + 255)/256, 256, 0, stream>>>(xs, H1_0, H2_0, DP);
    k_initPT<<<(2*2176*352 + 255)/256, 256, 0, stream>>>(xs, H1_0, H2_0, PT);

    KParams prm;
    prm.G16 = G16; prm.PT = PT; prm.DP = DP;
    prm.Wt = Wt; prm.Weff = Weff; prm.Mw = Mw; prm.tv = tv;
    prm.ZR = ZR; prm.Henc = Henc; prm.Hdec = Hdec;
    prm.xs = xs;
    prm.wL = wL; prm.bL = bL; prm.wH = wH; prm.bH = bH;
    prm.bcam = b_camH; prm.bagg = b_aggH; prm.Wfuse = Wf;
    prm.Wfc = W_fc; prm.bfc = b_fc;
    prm.out = (float*)d_out;

    int par = 0;
    for (int t = 0; t < TENC; t++) {
        g_diff<<<1428, 256, 0, stream>>>(prm, par, 2);
        g_proj0e<<<2*NGB*2, 256, 0, stream>>>(prm, par, t);
        par ^= 1;
        g_diff<<<1428, 256, 0, stream>>>(prm, par, 2);
        g_proj1e<<<NGB*2, 256, 0, stream>>>(prm, par, t);
        par ^= 1;
    }
    g_fuse<<<NGB, 256, 0, stream>>>(prm);
    for (int t = 0; t < TDEC; t++) {
        g_diff<<<714, 256, 0, stream>>>(prm, par, 1);
        g_proj0d<<<2*NGB, 256, 0, stream>>>(prm, par, t);
        par ^= 1;
        g_diff<<<714, 256, 0, stream>>>(prm, par, 1);
        g_proj1d<<<NGB, 256, 0, stream>>>(prm, par, t);
        par ^= 1;
    }
}

// Round 12
// 1161.360 us; speedup vs baseline: 5.4883x; 1.0247x over previous
//
#include <hip/hip_runtime.h>
#include <math.h>

#define NN 325
#define BB 32
#define NB (NN*BB)            // 10400
#define TENC 6
#define TDEC 12
#define WSET 65472            // fp32 Weff: Wzr(340x128)+Wc(340x64)+bzr(128)+bc(64)
#define WT_SET (192*352)      // f16 transposed weights per set
#define M_SET (325*192)       // Mzr[325][128] + Mc[325][64]
#define G16_MAT (384*352)
#define PT_B 765952ull        // 2176*352 f16 per buf
#define PT_E 1531904ull
#define DP_B 3660800ull       // 10400*352 f16 per buf
#define DP_E 7321600ull
#define NGB 176               // proj blocks: 11 n-groups x 16 b-pairs

typedef _Float16 f16;
typedef f16 f16x4 __attribute__((ext_vector_type(4)));
typedef f16 f16x8 __attribute__((ext_vector_type(8)));
typedef float f32x4 __attribute__((ext_vector_type(4)));

static constexpr float ALPHA = 0.05f;
static constexpr float BETA  = 0.95f;
static constexpr float GAMMA = 0.95f;
static constexpr float ISQ2  = 0.7071067811865476f;

// ---------------- workspace offsets (floats) ----------------
static constexpr size_t OFF_G    = 0;
static constexpr size_t OFF_RS   = OFF_G + 2ull*NN*NN;
static constexpr size_t OFF_RV   = OFF_RS + 650;
static constexpr size_t OFF_WEFF = OFF_RV + 1300;
static constexpr size_t OFF_WT   = OFF_WEFF + 3ull*WSET;
static constexpr size_t OFF_G16  = OFF_WT + (3ull*WT_SET)/2;
static constexpr size_t OFF_M    = OFF_G16 + (4ull*G16_MAT)/2;
static constexpr size_t OFF_WF   = OFF_M + 3ull*M_SET;          // 64*256 f16 -> 8192
static constexpr size_t OFF_TV   = OFF_WF + 8192;               // 576
static constexpr size_t OFF_XS   = OFF_TV + 576;
static constexpr size_t OFF_PT   = OFF_XS + (2ull*TENC*NB*4)/2;
static constexpr size_t OFF_DP   = OFF_PT + (2ull*PT_E)/2;
static constexpr size_t OFF_ZR   = OFF_DP + (2ull*DP_E)/2;      // 2*NB*64 fp32 (G2 alias)
static constexpr size_t OFF_HENC = OFF_ZR + 2ull*NB*64;
static constexpr size_t OFF_HDEC = OFF_HENC + 2ull*NB*64;

__device__ inline unsigned pk2(float a, float b) {
    union { f16 h[2]; unsigned u; } x;
    x.h[0] = (f16)a; x.h[1] = (f16)b; return x.u;
}
__device__ inline void st4h(f16* p, float a, float b, float c, float d) {
    f16x4 v; v[0]=(f16)a; v[1]=(f16)b; v[2]=(f16)c; v[3]=(f16)d;
    *(f16x4*)p = v;
}
__device__ inline f16x8 ld8_lds(const f16* p) {
    f16x4 lo = *(const f16x4*)p;
    f16x4 hi = *(const f16x4*)(p + 4);
    f16x8 r;
    r[0]=lo[0]; r[1]=lo[1]; r[2]=lo[2]; r[3]=lo[3];
    r[4]=hi[0]; r[5]=hi[1]; r[6]=hi[2]; r[7]=hi[3];
    return r;
}

// ---------------- prep ----------------
__global__ void k_sums(const float* __restrict__ adj, float* rs, float* cs) {
    int v = blockIdx.x; int t = threadIdx.x;
    float sr = 0.f, sc = 0.f;
    for (int w = t; w < NN; w += 64) { sr += adj[v*NN + w]; sc += adj[w*NN + v]; }
    for (int o = 32; o > 0; o >>= 1) { sr += __shfl_down(sr, o); sc += __shfl_down(sc, o); }
    if (t == 0) { rs[v] = sr + 1.0f; cs[v] = sc + 1.0f; }
}

__global__ void k_buildG(const float* __restrict__ adj, const float* __restrict__ P,
                         const float* __restrict__ rs, const float* __restrict__ cs,
                         float* __restrict__ G) {
    int idx = blockIdx.x*256 + threadIdx.x;
    if (idx >= NN*NN) return;
    int w = idx / NN, v = idx % NN;
    float d = (v == w) ? 1.0f : 0.0f;
    float a1  = (adj[v*NN + w] + d) / rs[v];
    float a1t = (adj[w*NN + v] + d) / cs[v];
    float p = P[v*NN + w];
    G[idx]         = BETA*a1  + GAMMA*p;
    G[NN*NN + idx] = BETA*a1t + GAMMA*p;
}

__global__ __launch_bounds__(256) void k_gg(const float* __restrict__ G, float* __restrict__ G2) {
    int g = blockIdx.z;
    const float* A = G + (size_t)g*NN*NN;
    float* C = G2 + (size_t)g*NN*NN;
    int n0 = blockIdx.y*32, j0 = blockIdx.x*32;
    int tx = threadIdx.x & 31, ty = threadIdx.x >> 5;
    __shared__ float As[32][33];
    __shared__ float Bs[32][33];
    float acc[4] = {};
    for (int k0 = 0; k0 < NN; k0 += 32) {
        for (int l = threadIdx.x; l < 32*32; l += 256) {
            int i = l >> 5, kk = l & 31;
            int n = n0 + i, k = k0 + kk;
            As[i][kk] = (n < NN && k < NN) ? A[(size_t)n*NN + k] : 0.0f;
            int j = j0 + kk;
            Bs[i][kk] = (k0 + i < NN && j < NN) ? A[(size_t)(k0+i)*NN + j] : 0.0f;
        }
        __syncthreads();
        #pragma unroll 8
        for (int kk = 0; kk < 32; kk++) {
            float bv = Bs[kk][tx];
            #pragma unroll
            for (int i = 0; i < 4; i++) acc[i] = fmaf(As[ty + 8*i][kk], bv, acc[i]);
        }
        __syncthreads();
    }
    #pragma unroll
    for (int i = 0; i < 4; i++) {
        int n = n0 + ty + 8*i, j = j0 + tx;
        if (n < NN && j < NN) C[(size_t)n*NN + j] = acc[i];
    }
}

// fused: g16 elementwise + rowsums (appended blocks)
__global__ void k_g16rs(const float* __restrict__ G, const float* __restrict__ G2,
                        f16* __restrict__ G16, float* __restrict__ rv) {
    const int GB = (4*G16_MAT + 255)/256;   // 2112
    if ((int)blockIdx.x < GB) {
        int idx = blockIdx.x*256 + threadIdx.x;
        if (idx >= 4*G16_MAT) return;
        int m = idx / G16_MAT;
        int rem = idx - m*G16_MAT;
        int n = rem / 352, v = rem - n*352;
        int g = m >> 1, s = m & 1;
        float val = 0.0f;
        if (n < NN && v < NN) {
            float gv = G[(size_t)g*NN*NN + n*NN + v];
            float d = (n == v) ? ALPHA : 0.0f;
            val = (s == 0) ? (gv + d)
                           : (G2[(size_t)g*NN*NN + n*NN + v] + ALPHA*gv + d);
        }
        G16[idx] = (f16)val;
    } else {
        int row = (blockIdx.x - GB)*4 + (threadIdx.x >> 6);
        int t = threadIdx.x & 63;
        if (row >= 650) return;
        int g = row / NN, n = row - g*NN;
        float s1 = 0.f, s2 = 0.f;
        for (int v = t; v < NN; v += 64) {
            s1 += G[(size_t)g*NN*NN + n*NN + v];
            s2 += G2[(size_t)g*NN*NN + n*NN + v];
        }
        for (int o = 32; o > 0; o >>= 1) { s1 += __shfl_down(s1, o); s2 += __shfl_down(s2, o); }
        if (t == 0) {
            rv[(g*2 + 0)*NN + n] = ALPHA + s1;
            rv[(g*2 + 1)*NN + n] = ALPHA + ALPHA*s1 + s2;
        }
    }
}

// fused misc: tv + xs16 + initH + weff3 (all independent elementwise)
__global__ void k_misc(const float* __restrict__ st, const float* __restrict__ x,
                       const float* __restrict__ H1_0, const float* __restrict__ H2_0,
                       const float* __restrict__ W0, const float* __restrict__ b0,
                       const float* __restrict__ W1, const float* __restrict__ b1,
                       const float* __restrict__ W2, const float* __restrict__ b2,
                       float* __restrict__ tv, f16* __restrict__ xs,
                       float* __restrict__ Henc, float* __restrict__ WeffAll) {
    const int N_TV = 18*32;
    const int N_XS = 2*TENC*NB*4;
    const int N_H  = 2*NB*64;
    const int N_W  = 3*WSET;
    int idx = blockIdx.x*256 + threadIdx.x;
    if (idx < N_TV) {
        int b = idx & 31, t = idx >> 5;
        float v;
        if (t < 6) {
            float hour   = (st[b*48 + 24 + 2*t] + 0.5f) * 23.0f;
            float minute = (st[b*48 + 36 + 2*t] + 0.5f) * 59.0f;
            v = floorf((hour*60.0f + minute) / 5.0f);
        } else {
            int td = t - 6;
            v = floorf((st[b*48 + 24 + td] + 0.5f) * 6.0f);
        }
        tv[idx] = v;
        return;
    }
    idx -= N_TV;
    if (idx < N_XS) {
        int c = idx & 3;
        int r = (idx >> 2) % NB;
        int t = (idx / (4*NB)) % TENC;
        int e = idx / (4*NB*TENC);
        int n = r / BB, b = r % BB;
        float val = 0.0f;
        if (c < 3) {
            float xe = x[((b*3 + c)*NN + n)*12 + 2*t];
            float xo = x[((b*3 + c)*NN + n)*12 + 2*t + 1];
            val = (e == 0) ? (xe - xo)*ISQ2 : (xe + xo)*ISQ2;
        }
        xs[idx] = (f16)val;
        return;
    }
    idx -= N_XS;
    if (idx < N_H) {
        int k = idx & 63;
        int r = (idx >> 6) % NB;
        int e = idx / (NB*64);
        int n = r / BB, b = r % BB;
        const float* src = e ? H2_0 : H1_0;
        Henc[idx] = src[((size_t)b*NN + n)*64 + k];
        return;
    }
    idx -= N_H;
    if (idx < N_W) {
        int s = idx / WSET;
        int u = idx - s*WSET;
        const float* W = (s == 0) ? W0 : (s == 1) ? W1 : W2;
        const float* b = (s == 0) ? b0 : (s == 1) ? b1 : b2;
        float* Wset = WeffAll + (size_t)s*WSET;
        if (u < 65280) {
            int k = u / 192, col = u - (u/192)*192;
            int g = col >> 6, oo = col & 63;
            const float* Wa = W + (2*g)*204*64;
            const float* Wb = W + (2*g+1)*204*64;
            float val;
            if (k < 68)       val = Wa[k*64+oo] + Wb[k*64+oo];
            else if (k < 204) val = Wa[k*64+oo];
            else              val = Wb[(k-136)*64+oo];
            if (g < 2) Wset[k*128 + g*64 + oo] = val;
            else       Wset[43520 + k*64 + oo] = val;
        } else {
            int col = u - 65280, g = col >> 6, oo = col & 63;
            float bv = b[(2*g)*64+oo] + b[(2*g+1)*64+oo];
            if (g < 2) Wset[65280 + col] = bv;
            else       Wset[65408 + oo] = bv;
        }
    }
}

// fused: wt3 + M3 + wfuse
__global__ void k_wtM(const float* __restrict__ WeffAll, const float* __restrict__ rv,
                      const float* __restrict__ Wcam, const float* __restrict__ Wagg,
                      f16* __restrict__ WtAll, float* __restrict__ MAll,
                      f16* __restrict__ Wf) {
    const int N_WT = 3*192*352;
    const int N_M  = 3*325*192;
    int idx = blockIdx.x*256 + threadIdx.x;
    if (idx < N_WT) {
        int s = idx / (192*352);
        int u = idx - s*(192*352);
        const float* Weff = WeffAll + (size_t)s*WSET;
        int o = u / 352, k = u - o*352;
        float v = 0.0f;
        if (k < 340) {
            int p = k / 68, c = k - p*68;
            if (c != 3) v = (o < 128) ? Weff[k*128 + o] : Weff[43520 + k*64 + (o - 128)];
        }
        WtAll[(size_t)s*WT_SET + u] = (f16)v;
        return;
    }
    idx -= N_WT;
    if (idx < N_M) {
        int s = idx / (325*192);
        int u = idx - s*(325*192);
        const float* Weff = WeffAll + (size_t)s*WSET;
        float* M = MAll + (size_t)s*M_SET;
        int n = u / 192, q = u - n*192;
        float acc;
        if (q < 128) {
            int o = q;
            acc = Weff[3*128 + o];
            #pragma unroll
            for (int p = 1; p <= 4; p++)
                acc += rv[(p-1)*NN + n] * Weff[(p*68 + 3)*128 + o];
            M[(size_t)n*128 + o] = acc;
        } else {
            int o = q - 128;
            acc = Weff[43520 + 3*64 + o];
            #pragma unroll
            for (int p = 1; p <= 4; p++)
                acc += rv[(p-1)*NN + n] * Weff[43520 + (p*68 + 3)*64 + o];
            M[325*128 + (size_t)n*64 + o] = acc;
        }
        return;
    }
    idx -= N_M;
    if (idx < 64*256) {
        int o = idx >> 8, k = idx & 255;
        float v = (k < 128) ? 0.3f*Wcam[(size_t)k*64 + o]
                            : 0.7f*Wagg[(size_t)(k-128)*64 + o];
        Wf[(size_t)o*256 + k] = (f16)v;
    }
}

// fused: initDP + initPT
__global__ void k_init2(const f16* __restrict__ xs, const float* __restrict__ H1_0,
                        const float* __restrict__ H2_0,
                        f16* __restrict__ DP, f16* __restrict__ PTb) {
    const int N_DP = 2*NB*92;
    int idx = blockIdx.x*256 + threadIdx.x;
    if (idx < N_DP) {
        int cc = idx % 92;
        int r = (idx / 92) % NB;
        int e = idx / (92*NB);
        int n = r >> 5, b = r & 31;
        f16* D0 = DP + (size_t)e*DP_E;
        if (cc < 68) {
            f16 v;
            if (cc < 3)       v = xs[(size_t)e*TENC*NB*4 + (size_t)r*4 + cc];
            else if (cc == 3) v = (f16)0.0f;
            else {
                const float* h0 = e ? H2_0 : H1_0;
                v = (f16)h0[((size_t)b*NN + n)*64 + (cc-4)];
            }
            D0[(size_t)r*352 + cc] = v;
        } else if (cc < 80) {
            D0[(size_t)r*352 + 340 + (cc-68)] = (f16)0.0f;
        } else {
            D0[DP_B + (size_t)r*352 + 340 + (cc-80)] = (f16)0.0f;
        }
        return;
    }
    idx -= N_DP;
    if (idx < 2*2176*352) {
        int v = idx % 352;
        int j = (idx / 352) % 2176;
        int e = idx / (352*2176);
        f16* P0 = PTb + (size_t)e*PT_E;
        if (v >= NN) {
            P0[(size_t)j*352 + v] = (f16)0.0f;
            P0[PT_B + (size_t)j*352 + v] = (f16)0.0f;
            return;
        }
        int b = j / 68, c = j - b*68;
        f16 val;
        if (c < 3)       val = xs[(size_t)e*TENC*NB*4 + (size_t)(v*32+b)*4 + c];
        else if (c == 3) val = (f16)0.0f;
        else {
            const float* h0 = e ? H2_0 : H1_0;
            val = (f16)h0[((size_t)b*NN + v)*64 + (c-4)];
        }
        P0[(size_t)j*352 + v] = val;
    }
}

// ================= phases =================
struct KParams {
    const f16* G16;
    f16* PT;
    f16* DP;
    const f16* Wt;
    const float* Weff;
    const float* Mw;
    const float* tv;
    float* ZR;
    float* Henc;
    float* Hdec;
    const f16* xs;
    const float* wL; const float* bL; const float* wH; const float* bH;
    const float* bcam; const float* bagg;
    const f16* Wfuse;
    const float* Wfc; const float* bfc;
    float* out;
};

// diff with R-tile 128: A-frags (PT rows) loaded once, used for both R-halves.
__device__ void phase_diff(const KParams& p, int par, int E) {
    int tid = threadIdx.x;
    int lane = tid & 63, w = tid >> 6;
    int wm = w >> 1, wn = w & 1;
    int l15 = lane & 15, lk = lane >> 4;
    int ntiles = 34*11*E;
    for (int idx = blockIdx.x; idx < ntiles; idx += gridDim.x) {
        int jt = idx % 34, rem = idx / 34;
        int Rt = rem % 11, e = rem / 11;
        const f16* X = p.PT + (size_t)e*PT_E + (size_t)par*PT_B;
        f16* D = p.DP + (size_t)e*DP_E + (size_t)par*DP_B;
        int j0 = jt*64, R0 = Rt*128;
        const f16* ap[2];
        #pragma unroll
        for (int a = 0; a < 2; a++)
            ap[a] = X + (size_t)(j0 + wm*32 + a*16 + l15)*352;
        const f16* bp[2][2]; int mv[2][2], nv[2][2];
        #pragma unroll
        for (int rg = 0; rg < 2; rg++)
            #pragma unroll
            for (int bt = 0; bt < 2; bt++) {
                int R = R0 + rg*64 + wn*32 + bt*16 + l15;
                int ok = (R < 1300);
                int Rc = ok ? R : 0;
                int m = Rc / 325, n = Rc - m*325;
                mv[rg][bt] = ok ? m : -1; nv[rg][bt] = n;
                bp[rg][bt] = p.G16 + (size_t)m*G16_MAT + (size_t)n*352;
            }
        f32x4 acc[2][2][2] = {};
        #pragma unroll
        for (int k0 = 0; k0 < 352; k0 += 32) {
            f16x8 af[2];
            #pragma unroll
            for (int a = 0; a < 2; a++) af[a] = *(const f16x8*)(ap[a] + k0 + lk*8);
            #pragma unroll
            for (int rg = 0; rg < 2; rg++) {
                f16x8 bf[2];
                #pragma unroll
                for (int bt = 0; bt < 2; bt++) bf[bt] = *(const f16x8*)(bp[rg][bt] + k0 + lk*8);
                #pragma unroll
                for (int a = 0; a < 2; a++)
                    #pragma unroll
                    for (int bt = 0; bt < 2; bt++)
                        acc[rg][a][bt] = __builtin_amdgcn_mfma_f32_16x16x32_f16(af[a], bf[bt], acc[rg][a][bt], 0,0,0);
            }
        }
        #pragma unroll
        for (int rg = 0; rg < 2; rg++)
            #pragma unroll
            for (int bt = 0; bt < 2; bt++) {
                if (mv[rg][bt] < 0) continue;
                int m = mv[rg][bt], n = nv[rg][bt];
                #pragma unroll
                for (int a = 0; a < 2; a++) {
                    int jb = j0 + wm*32 + a*16 + lk*4;
                    int b = jb / 68, c = jb - b*68;
                    f16* dst = D + (size_t)(n*32 + b)*352 + (m+1)*68 + c;
                    st4h(dst, acc[rg][a][bt][0], acc[rg][a][bt][1],
                              acc[rg][a][bt][2], acc[rg][a][bt][3]);
                }
            }
    }
}

// proj0 with merged o-halves: block computes all 128 outputs (z + r) per row-tile.
__device__ void phase_proj0(const KParams& p, int par, int E,
        const f16* WtB, int wt_str, const float* biasB, int bias_str,
        const float* MB, int m_str, const float* tvp, float* HstB) {
    int tid = threadIdx.x;
    int lane = tid & 63, w = tid >> 6;
    int wm = w >> 1, wn = w & 1;
    int l15 = lane & 15, lk = lane >> 4;
    int ntiles = NGB*E;
    for (int idx = blockIdx.x; idx < ntiles; idx += gridDim.x) {
        int rt = idx % NGB, e = idx / NGB;
        int ng = rt >> 4, bpx = rt & 15;
        const f16* Wt = WtB + (size_t)e*wt_str;
        const float* bias = biasB + (size_t)e*bias_str + 65280;
        const float* M = MB + (size_t)e*m_str;
        const f16* Dc = p.DP + (size_t)e*DP_E + (size_t)par*DP_B;
        f16* Dn = p.DP + (size_t)e*DP_E + (size_t)(par^1)*DP_B;
        f16* PTn = p.PT + (size_t)e*PT_E + (size_t)(par^1)*PT_B;
        float* ZR = p.ZR + (size_t)e*NB*64;
        float* Hs = HstB + (size_t)e*NB*64;
        int bcol = bpx*2 + wn;
        const f16* ap[4]; const f16* bfp[2];
        #pragma unroll
        for (int a = 0; a < 4; a++)
            ap[a] = Wt + (size_t)(a*32 + wm*16 + l15)*352;
        #pragma unroll
        for (int bt = 0; bt < 2; bt++) {
            int n = ng*32 + bt*16 + l15;
            int rc = (n < NN) ? (n*32 + bcol) : 0;
            bfp[bt] = Dc + (size_t)rc*352;
        }
        f32x4 acc[4][2] = {};
        #pragma unroll
        for (int k0 = 0; k0 < 352; k0 += 32) {
            f16x8 af[4], bf[2];
            #pragma unroll
            for (int a = 0; a < 4; a++) af[a] = *(const f16x8*)(ap[a] + k0 + lk*8);
            #pragma unroll
            for (int bt = 0; bt < 2; bt++) bf[bt] = *(const f16x8*)(bfp[bt] + k0 + lk*8);
            #pragma unroll
            for (int a = 0; a < 4; a++)
                #pragma unroll
                for (int bt = 0; bt < 2; bt++)
                    acc[a][bt] = __builtin_amdgcn_mfma_f32_16x16x32_f16(af[a], bf[bt], acc[a][bt], 0,0,0);
        }
        #pragma unroll
        for (int bt = 0; bt < 2; bt++) {
            int n = ng*32 + bt*16 + l15;
            if (n < NN) {
                int b = bcol;
                int r = n*32 + b;
                float tvb = tvp[b];
                #pragma unroll
                for (int a = 0; a < 4; a++) {
                    int oo = a*32 + wm*16 + lk*4;
                    float4 bs = *(const float4*)(bias + oo);
                    float4 ms = *(const float4*)(M + (size_t)n*128 + oo);
                    float p0 = acc[a][bt][0] + bs.x + tvb*ms.x;
                    float p1 = acc[a][bt][1] + bs.y + tvb*ms.y;
                    float p2 = acc[a][bt][2] + bs.z + tvb*ms.z;
                    float p3 = acc[a][bt][3] + bs.w + tvb*ms.w;
                    float s0 = 1.0f/(1.0f+expf(-p0)), s1 = 1.0f/(1.0f+expf(-p1));
                    float s2 = 1.0f/(1.0f+expf(-p2)), s3 = 1.0f/(1.0f+expf(-p3));
                    if (oo < 64) {
                        *(float4*)(ZR + (size_t)r*64 + oo) = make_float4(s0,s1,s2,s3);
                    } else {
                        int oh = oo - 64;
                        float4 h4 = *(const float4*)(Hs + (size_t)r*64 + oh);
                        float g0 = s0*h4.x, g1 = s1*h4.y, g2 = s2*h4.z, g3 = s3*h4.w;
                        st4h(Dn + (size_t)r*352 + 4 + oh, g0, g1, g2, g3);
                        size_t pb = (size_t)(b*68 + 4 + oh)*352 + n;
                        PTn[pb]       = (f16)g0;
                        PTn[pb + 352] = (f16)g1;
                        PTn[pb + 704] = (f16)g2;
                        PTn[pb + 1056]= (f16)g3;
                    }
                }
            }
        }
        {
            int n_l = tid & 31, b_l = (tid >> 5) & 1, q = tid >> 6;
            int n = ng*32 + n_l;
            if (n < NN) {
                int b = bpx*2 + b_l;
                int r = n*32 + b;
                f16 v = Dc[(size_t)r*352 + q];
                Dn[(size_t)r*352 + q] = v;
                PTn[(size_t)(b*68 + q)*352 + n] = v;
            }
        }
    }
}

__device__ void phase_proj1_enc(const KParams& p, int par, int t) {
    int tid = threadIdx.x;
    int lane = tid & 63, w = tid >> 6;
    int wm = w >> 1, wn = w & 1;
    int l15 = lane & 15, lk = lane >> 4;
    int ntiles = NGB*2;
    for (int idx = blockIdx.x; idx < ntiles; idx += gridDim.x) {
        int rt = idx % NGB, e = idx / NGB;
        int ng = rt >> 4, bpx = rt & 15;
        const f16* Wt = p.Wt + (size_t)e*WT_SET + 128*352;
        const float* bias = p.Weff + (size_t)e*WSET + 65408;
        const float* M = p.Mw + (size_t)e*M_SET + 325*128;
        const f16* Dc = p.DP + (size_t)e*DP_E + (size_t)par*DP_B;
        f16* Dn = p.DP + (size_t)e*DP_E + (size_t)(par^1)*DP_B;
        f16* PTn = p.PT + (size_t)e*PT_E + (size_t)(par^1)*PT_B;
        float* ZR = p.ZR + (size_t)e*NB*64;
        float* Hs = p.Henc + (size_t)e*NB*64;
        const float* tvv = p.tv + (size_t)t*32;
        int bcol = bpx*2 + wn;
        const f16* ap[2]; const f16* bfp[2];
        #pragma unroll
        for (int a = 0; a < 2; a++) ap[a] = Wt + (size_t)(wm*32 + a*16 + l15)*352;
        #pragma unroll
        for (int bt = 0; bt < 2; bt++) {
            int n = ng*32 + bt*16 + l15;
            int rc = (n < NN) ? (n*32 + bcol) : 0;
            bfp[bt] = Dc + (size_t)rc*352;
        }
        f32x4 acc[2][2] = {};
        #pragma unroll
        for (int k0 = 0; k0 < 352; k0 += 32) {
            f16x8 af[2], bf[2];
            #pragma unroll
            for (int a = 0; a < 2; a++) af[a] = *(const f16x8*)(ap[a] + k0 + lk*8);
            #pragma unroll
            for (int bt = 0; bt < 2; bt++) bf[bt] = *(const f16x8*)(bfp[bt] + k0 + lk*8);
            #pragma unroll
            for (int a = 0; a < 2; a++)
                #pragma unroll
                for (int bt = 0; bt < 2; bt++)
                    acc[a][bt] = __builtin_amdgcn_mfma_f32_16x16x32_f16(af[a], bf[bt], acc[a][bt], 0,0,0);
        }
        #pragma unroll
        for (int bt = 0; bt < 2; bt++) {
            int n = ng*32 + bt*16 + l15;
            if (n < NN) {
                int b = bcol;
                int r = n*32 + b;
                float tvb = tvv[b];
                #pragma unroll
                for (int a = 0; a < 2; a++) {
                    int oo = wm*32 + a*16 + lk*4;
                    float4 bs = *(const float4*)(bias + oo);
                    float4 ms = *(const float4*)(M + (size_t)n*64 + oo);
                    float p0 = acc[a][bt][0] + bs.x + tvb*ms.x;
                    float p1 = acc[a][bt][1] + bs.y + tvb*ms.y;
                    float p2 = acc[a][bt][2] + bs.z + tvb*ms.z;
                    float p3 = acc[a][bt][3] + bs.w + tvb*ms.w;
                    float4 z4 = *(const float4*)(ZR + (size_t)r*64 + oo);
                    float4 h4 = *(const float4*)(Hs + (size_t)r*64 + oo);
                    float h0 = z4.x*h4.x + (1.0f - z4.x)*tanhf(p0);
                    float h1 = z4.y*h4.y + (1.0f - z4.y)*tanhf(p1);
                    float h2 = z4.z*h4.z + (1.0f - z4.z)*tanhf(p2);
                    float h3 = z4.w*h4.w + (1.0f - z4.w)*tanhf(p3);
                    *(float4*)(Hs + (size_t)r*64 + oo) = make_float4(h0,h1,h2,h3);
                    st4h(Dn + (size_t)r*352 + 4 + oo, h0, h1, h2, h3);
                    size_t pb = (size_t)(b*68 + 4 + oo)*352 + n;
                    PTn[pb]       = (f16)h0;
                    PTn[pb + 352] = (f16)h1;
                    PTn[pb + 704] = (f16)h2;
                    PTn[pb + 1056]= (f16)h3;
                }
            }
        }
        const f16* xn = nullptr;
        if (t < TENC-1) xn = p.xs + (size_t)(e*TENC + t + 1)*NB*4;
        if (xn) {
            int n_l = tid & 31, b_l = (tid >> 5) & 1, q = tid >> 6;
            int n = ng*32 + n_l;
            if (n < NN) {
                int b = bpx*2 + b_l;
                int r = n*32 + b;
                f16 v = (q < 3) ? xn[(size_t)r*4 + q] : (f16)0.0f;
                Dn[(size_t)r*352 + q] = v;
                PTn[(size_t)(b*68 + q)*352 + n] = v;
            }
        }
    }
}

__device__ void phase_proj1_dec(const KParams& p, int par, int t, f16* smem) {
    int tid = threadIdx.x;
    int lane = tid & 63, w = tid >> 6;
    int wm = w >> 1, wn = w & 1;
    int l15 = lane & 15, lk = lane >> 4;
    const f16* Wt = p.Wt + 2*WT_SET + 128*352;
    const float* bias = p.Weff + 2*WSET + 65408;
    const float* M = p.Mw + 2*M_SET + 325*128;
    const f16* Dc = p.DP + (size_t)par*DP_B;
    f16* Dn = p.DP + (size_t)(par^1)*DP_B;
    f16* PTn = p.PT + (size_t)(par^1)*PT_B;
    const float* tvv = p.tv + (size_t)(6 + t)*32;
    for (int idx = blockIdx.x; idx < NGB; idx += gridDim.x) {
        int ng = idx >> 4, bpx = idx & 15;
        int bcol = bpx*2 + wn;
        const f16* ap[2]; const f16* bfp[2];
        #pragma unroll
        for (int a = 0; a < 2; a++) ap[a] = Wt + (size_t)(wm*32 + a*16 + l15)*352;
        #pragma unroll
        for (int bt = 0; bt < 2; bt++) {
            int n = ng*32 + bt*16 + l15;
            int rc = (n < NN) ? (n*32 + bcol) : 0;
            bfp[bt] = Dc + (size_t)rc*352;
        }
        f32x4 acc[2][2] = {};
        #pragma unroll
        for (int k0 = 0; k0 < 352; k0 += 32) {
            f16x8 af[2], bf[2];
            #pragma unroll
            for (int a = 0; a < 2; a++) af[a] = *(const f16x8*)(ap[a] + k0 + lk*8);
            #pragma unroll
            for (int bt = 0; bt < 2; bt++) bf[bt] = *(const f16x8*)(bfp[bt] + k0 + lk*8);
            #pragma unroll
            for (int a = 0; a < 2; a++)
                #pragma unroll
                for (int bt = 0; bt < 2; bt++)
                    acc[a][bt] = __builtin_amdgcn_mfma_f32_16x16x32_f16(af[a], bf[bt], acc[a][bt], 0,0,0);
        }
        #pragma unroll
        for (int bt = 0; bt < 2; bt++) {
            int n = ng*32 + bt*16 + l15;
            int sl = wn*32 + bt*16 + l15;
            if (n < NN) {
                int b = bcol;
                int r = n*32 + b;
                float tvb = tvv[b];
                #pragma unroll
                for (int a = 0; a < 2; a++) {
                    int oo = wm*32 + a*16 + lk*4;
                    float4 bs = *(const float4*)(bias + oo);
                    float4 ms = *(const float4*)(M + (size_t)n*64 + oo);
                    float p0 = acc[a][bt][0] + bs.x + tvb*ms.x;
                    float p1 = acc[a][bt][1] + bs.y + tvb*ms.y;
                    float p2 = acc[a][bt][2] + bs.z + tvb*ms.z;
                    float p3 = acc[a][bt][3] + bs.w + tvb*ms.w;
                    float4 z4 = *(const float4*)(p.ZR + (size_t)r*64 + oo);
                    float4 h4 = *(const float4*)(p.Hdec + (size_t)r*64 + oo);
                    float h0 = z4.x*h4.x + (1.0f - z4.x)*tanhf(p0);
                    float h1 = z4.y*h4.y + (1.0f - z4.y)*tanhf(p1);
                    float h2 = z4.z*h4.z + (1.0f - z4.z)*tanhf(p2);
                    float h3 = z4.w*h4.w + (1.0f - z4.w)*tanhf(p3);
                    *(float4*)(p.Hdec + (size_t)r*64 + oo) = make_float4(h0,h1,h2,h3);
                    st4h(Dn + (size_t)r*352 + 4 + oo, h0, h1, h2, h3);
                    size_t pb = (size_t)(b*68 + 4 + oo)*352 + n;
                    PTn[pb]       = (f16)h0;
                    PTn[pb + 352] = (f16)h1;
                    PTn[pb + 704] = (f16)h2;
                    PTn[pb + 1056]= (f16)h3;
                    st4h(smem + sl*68 + oo, h0, h1, h2, h3);
                }
            }
        }
        __syncthreads();
        for (int q = tid; q < 192; q += 256) {
            int slot = q & 63, c = q >> 6;
            int n = ng*32 + (slot & 31);
            if (n < NN) {
                int b = bpx*2 + (slot >> 5);
                int r = n*32 + b;
                float a = p.bfc[c];
                #pragma unroll 8
                for (int k = 0; k < 64; k++)
                    a = fmaf((float)smem[slot*68 + k], p.Wfc[k*3 + c], a);
                int qq = t*3 + c;
                int oq = qq / 12, lq = qq - oq*12;
                p.out[(((size_t)b*3 + oq)*NN + n)*12 + lq] = a;
                if (t < TDEC-1) {
                    Dn[(size_t)r*352 + c] = (f16)a;
                    PTn[(size_t)((size_t)(b*68 + c))*352 + n] = (f16)a;
                }
            }
        }
        if (t < TDEC-1 && tid < 64) {
            int slot = tid;
            int n = ng*32 + (slot & 31);
            if (n < NN) {
                int b = bpx*2 + (slot >> 5);
                int r = n*32 + b;
                Dn[(size_t)r*352 + 3] = (f16)0.0f;
                PTn[(size_t)(b*68 + 3)*352 + n] = (f16)0.0f;
            }
        }
        __syncthreads();
    }
}

__device__ void phase_fuse(const KParams& p, f16* smem) {
    int tid = threadIdx.x;
    int lane = tid & 63, wave = tid >> 6;
    int wm = wave >> 1, wn = wave & 1;
    int l15 = lane & 15, lk = lane >> 4;
    const float* H1 = p.Henc;
    const float* H2 = p.Henc + (size_t)NB*64;
    unsigned* La = (unsigned*)smem;
    f16* Dn = p.DP;
    f16* PTn = p.PT;
    for (int idx = blockIdx.x; idx < NGB; idx += gridDim.x) {
        int ng = idx >> 4, bpx = idx & 15;
        for (int l = tid; l < 64*64; l += 256) {
            int i = l >> 6, k = l & 63;
            int n = ng*32 + (i & 31);
            unsigned val = 0;
            if (n < NN) {
                int b = bpx*2 + (i >> 5);
                int r = n*32 + b;
                float h1 = H1[(size_t)r*64 + k], h2 = H2[(size_t)r*64 + k];
                float s = h1 + h2;
                val = pk2(s*p.wL[n*64+k] + 2.0f*p.bL[n*64+k],
                          s*p.wH[n*64+k] + 2.0f*p.bH[n*64+k]);
            }
            La[i*132 + k] = val;
        }
        for (int l = tid; l < 64*32; l += 256) {
            int i = l >> 5, kp = l & 31;
            int n = ng*32 + (i & 31);
            unsigned v1 = 0, v2 = 0;
            if (n < NN) {
                int b = bpx*2 + (i >> 5);
                int r = n*32 + b;
                float2 a = *(const float2*)(H1 + (size_t)r*64 + 2*kp);
                float2 b2 = *(const float2*)(H2 + (size_t)r*64 + 2*kp);
                v1 = pk2(a.x, a.y);
                v2 = pk2(b2.x, b2.y);
            }
            La[i*132 + 64 + kp] = v1;
            La[i*132 + 96 + kp] = v2;
        }
        __syncthreads();
        f32x4 acc[2][2] = {};
        for (int k0 = 0; k0 < 256; k0 += 32) {
            f16x8 afr[2], bfr[2];
            #pragma unroll
            for (int a = 0; a < 2; a++)
                afr[a] = *(const f16x8*)(p.Wfuse + (size_t)(wn*32 + a*16 + l15)*256 + k0 + lk*8);
            #pragma unroll
            for (int bt = 0; bt < 2; bt++)
                bfr[bt] = ld8_lds(smem + (wm*32 + bt*16 + l15)*264 + k0 + lk*8);
            #pragma unroll
            for (int a = 0; a < 2; a++)
                #pragma unroll
                for (int bt = 0; bt < 2; bt++)
                    acc[a][bt] = __builtin_amdgcn_mfma_f32_16x16x32_f16(afr[a], bfr[bt], acc[a][bt], 0,0,0);
        }
        __syncthreads();
        #pragma unroll
        for (int bt = 0; bt < 2; bt++) {
            int i = wm*32 + bt*16 + l15;
            int n = ng*32 + (i & 31);
            if (n < NN) {
                int b = bpx*2 + (i >> 5);
                int r = n*32 + b;
                #pragma unroll
                for (int a = 0; a < 2; a++) {
                    int ob = wn*32 + a*16 + lk*4;
                    float v0 = acc[a][bt][0] + 0.3f*p.bcam[ob]   + 0.7f*p.bagg[ob];
                    float v1 = acc[a][bt][1] + 0.3f*p.bcam[ob+1] + 0.7f*p.bagg[ob+1];
                    float v2 = acc[a][bt][2] + 0.3f*p.bcam[ob+2] + 0.7f*p.bagg[ob+2];
                    float v3 = acc[a][bt][3] + 0.3f*p.bcam[ob+3] + 0.7f*p.bagg[ob+3];
                    *(float4*)(p.Hdec + (size_t)r*64 + ob) = make_float4(v0,v1,v2,v3);
                    st4h(Dn + (size_t)r*352 + 4 + ob, v0, v1, v2, v3);
                    size_t pb = (size_t)(b*68 + 4 + ob)*352 + n;
                    PTn[pb]       = (f16)v0;
                    PTn[pb + 352] = (f16)v1;
                    PTn[pb + 704] = (f16)v2;
                    PTn[pb + 1056]= (f16)v3;
                }
            }
        }
        {
            int n_l = tid & 31, b_l = (tid >> 5) & 1, q = tid >> 6;
            int n = ng*32 + n_l;
            if (n < NN) {
                int b = bpx*2 + b_l;
                int r = n*32 + b;
                Dn[(size_t)r*352 + q] = (f16)0.0f;
                PTn[(size_t)(b*68 + q)*352 + n] = (f16)0.0f;
            }
        }
        __syncthreads();
    }
}

// ---------------- wrappers (split launches) ----------------
__global__ __launch_bounds__(256) void g_diff(KParams p, int par, int E) { phase_diff(p, par, E); }
__global__ __launch_bounds__(256) void g_proj0e(KParams p, int par, int t) {
    phase_proj0(p, par, 2, p.Wt, WT_SET, p.Weff, WSET, p.Mw, M_SET,
                p.tv + (size_t)t*32, p.Henc);
}
__global__ __launch_bounds__(256) void g_proj0d(KParams p, int par, int t) {
    phase_proj0(p, par, 1, p.Wt + 2*WT_SET, 0, p.Weff + 2*WSET, 0,
                p.Mw + 2*M_SET, 0, p.tv + (size_t)(6 + t)*32, p.Hdec);
}
__global__ __launch_bounds__(256) void g_proj1e(KParams p, int par, int t) { phase_proj1_enc(p, par, t); }
__global__ __launch_bounds__(256) void g_proj1d(KParams p, int par, int t) {
    __shared__ f16 smem[64*68];
    phase_proj1_dec(p, par, t, smem);
}
__global__ __launch_bounds__(256) void g_fuse(KParams p) {
    __shared__ f16 smem[64*264];
    phase_fuse(p, smem);
}

// ---------------- host ----------------
extern "C" void kernel_launch(void* const* d_in, const int* in_sizes, int n_in,
                              void* d_out, int out_size, void* d_ws, size_t ws_size,
                              hipStream_t stream) {
    const float* x      = (const float*)d_in[0];
    const float* st     = (const float*)d_in[1];
    const float* adj    = (const float*)d_in[2];
    const float* P      = (const float*)d_in[3];
    const float* H1_0   = (const float*)d_in[4];
    const float* H2_0   = (const float*)d_in[6];
    const float* W_encD = (const float*)d_in[8];
    const float* b_encD = (const float*)d_in[9];
    const float* W_encAD= (const float*)d_in[10];
    const float* b_encAD= (const float*)d_in[11];
    const float* W_dec  = (const float*)d_in[12];
    const float* b_dec  = (const float*)d_in[13];
    const float* W_fc   = (const float*)d_in[14];
    const float* b_fc   = (const float*)d_in[15];
    const float* W_aggH = (const float*)d_in[16];
    const float* b_aggH = (const float*)d_in[17];
    const float* W_camH = (const float*)d_in[20];
    const float* b_camH = (const float*)d_in[21];
    const float* wL     = (const float*)d_in[24];
    const float* bL     = (const float*)d_in[25];
    const float* wH     = (const float*)d_in[26];
    const float* bH     = (const float*)d_in[27];

    float* ws   = (float*)d_ws;
    float* G    = ws + OFF_G;
    float* rs   = ws + OFF_RS;
    float* cs   = rs + NN;
    float* rv   = ws + OFF_RV;
    float* Weff = ws + OFF_WEFF;
    f16*   Wt   = (f16*)(ws + OFF_WT);
    f16*   G16  = (f16*)(ws + OFF_G16);
    float* Mw   = ws + OFF_M;
    f16*   Wf   = (f16*)(ws + OFF_WF);
    float* tv   = ws + OFF_TV;
    f16*   xs   = (f16*)(ws + OFF_XS);
    f16*   PT   = (f16*)(ws + OFF_PT);
    f16*   DP   = (f16*)(ws + OFF_DP);
    float* ZR   = ws + OFF_ZR;
    float* G2   = ZR;
    float* Henc = ws + OFF_HENC;
    float* Hdec = ws + OFF_HDEC;

    // ---- prep (7 launches) ----
    k_sums<<<NN, 64, 0, stream>>>(adj, rs, cs);
    k_buildG<<<(NN*NN + 255)/256, 256, 0, stream>>>(adj, P, rs, cs, G);
    k_gg<<<dim3(11,11,2), 256, 0, stream>>>(G, G2);
    k_g16rs<<<(4*G16_MAT + 255)/256 + 163, 256, 0, stream>>>(G, G2, G16, rv);
    k_misc<<<(18*32 + 2*TENC*NB*4 + 2*NB*64 + 3*WSET + 255)/256, 256, 0, stream>>>(
        st, x, H1_0, H2_0, W_encD, b_encD, W_encAD, b_encAD, W_dec, b_dec,
        tv, xs, Henc, Weff);
    k_wtM<<<(3*192*352 + 3*325*192 + 64*256 + 255)/256, 256, 0, stream>>>(
        Weff, rv, W_camH, W_aggH, Wt, Mw, Wf);
    k_init2<<<(2*NB*92 + 2*2176*352 + 255)/256, 256, 0, stream>>>(xs, H1_0, H2_0, DP, PT);

    KParams prm;
    prm.G16 = G16; prm.PT = PT; prm.DP = DP;
    prm.Wt = Wt; prm.Weff = Weff; prm.Mw = Mw; prm.tv = tv;
    prm.ZR = ZR; prm.Henc = Henc; prm.Hdec = Hdec;
    prm.xs = xs;
    prm.wL = wL; prm.bL = bL; prm.wH = wH; prm.bH = bH;
    prm.bcam = b_camH; prm.bagg = b_aggH; prm.Wfuse = Wf;
    prm.Wfc = W_fc; prm.bfc = b_fc;
    prm.out = (float*)d_out;

    int par = 0;
    for (int t = 0; t < TENC; t++) {
        g_diff<<<748, 256, 0, stream>>>(prm, par, 2);
        g_proj0e<<<NGB*2, 256, 0, stream>>>(prm, par, t);
        par ^= 1;
        g_diff<<<748, 256, 0, stream>>>(prm, par, 2);
        g_proj1e<<<NGB*2, 256, 0, stream>>>(prm, par, t);
        par ^= 1;
    }
    g_fuse<<<NGB, 256, 0, stream>>>(prm);
    for (int t = 0; t < TDEC; t++) {
        g_diff<<<374, 256, 0, stream>>>(prm, par, 1);
        g_proj0d<<<NGB, 256, 0, stream>>>(prm, par, t);
        par ^= 1;
        g_diff<<<374, 256, 0, stream>>>(prm, par, 1);
        g_proj1d<<<NGB, 256, 0, stream>>>(prm, par, t);
        par ^= 1;
    }
}